// Round 4
// baseline (276.991 us; speedup 1.0000x reference)
//
#include <hip/hip_runtime.h>
#include <hip/hip_bf16.h>
#include <stdint.h>

// Problem constants (reference: N=20000, E=640000, C=D=M=128)
#define DIM 128
#define HSTR 136    // padded LDS row stride in fp16 elems (272 B, 16B-aligned rows)
#define H2STR 72    // h2t row stride in fp16 elems (144 B, 16B-aligned rows)
#define SSTR 132    // S_lds row stride in fp32 (2-way bank alias only)
#define NPB 16      // nodes per block in fused edge kernel
#define NMAX 20224  // LDS-staged scan capacity

using hfrag = __attribute__((ext_vector_type(8))) _Float16;  // 8 fp16 (4 VGPRs)
using h2v   = __attribute__((ext_vector_type(2))) _Float16;
using f32x4 = __attribute__((ext_vector_type(4))) float;     // MFMA C/D

__device__ __forceinline__ float prelu_f(float v, float a) { return v >= 0.f ? v : a * v; }

// pack 2 floats -> fp16x2 (RTZ, 1 inst). Builtin returns __fp16x2; bitcast.
__device__ __forceinline__ unsigned pkh(float a, float b) {
    auto h = __builtin_amdgcn_cvt_pkrtz(a, b);
    return *(unsigned*)&h;
}
__device__ __forceinline__ unsigned short hs(float v) {
    _Float16 h = (_Float16)v;
    return *(unsigned short*)&h;
}
// packed fp16 prelu of (s+g): min(h,0)*a + max(h,0)
__device__ __forceinline__ unsigned prelu2_add(unsigned su, unsigned gu, h2v a2) {
    h2v s = *(h2v*)&su, g = *(h2v*)&gu;
    h2v h = s + g;
    h2v z = {(_Float16)0.f, (_Float16)0.f};
    h2v mx = __builtin_elementwise_max(h, z);
    h2v mn = __builtin_elementwise_min(h, z);
    h2v r = mn * a2 + mx;
    return *(unsigned*)&r;
}

// ---------------------------------------------------------------------------
// Merged prep + hist. Hist also captures per-edge rank (coalesced store),
// so the later scatter needs NO atomics. Wall[m][n][k] = fp16(W_m[k][n]).
// ---------------------------------------------------------------------------
__global__ __launch_bounds__(256) void prep_hist_k(
    const float* __restrict__ Wsrc, const float* __restrict__ Wtgt,
    const float* __restrict__ Wskip, const float* __restrict__ W1,
    const float* __restrict__ W2, const float* __restrict__ b2,
    const float* __restrict__ Wg,
    unsigned short* __restrict__ Wall, float* __restrict__ w2g,
    const int* __restrict__ eidx, int E, int* __restrict__ deg,
    int* __restrict__ rank)
{
    const int nhist = (E + 255) / 256;
    if ((int)blockIdx.x < nhist) {
        const int e = blockIdx.x * 256 + threadIdx.x;
        if (e < E) rank[e] = atomicAdd(deg + eidx[(size_t)E + e], 1);
        return;
    }
    const int b = blockIdx.x - nhist;
    if (b == (5 * DIM * DIM) / 256) {   // w2g block
        const int k = threadIdx.x;
        if (k < DIM) {
            float s = 0.f;
            for (int d = 0; d < DIM; ++d) s += W2[k * DIM + d] * Wg[d];
            w2g[k] = s;
        } else if (k == DIM) {
            float s = 0.f;
            for (int d = 0; d < DIM; ++d) s += b2[d] * Wg[d];
            w2g[DIM] = s;
        }
        return;
    }
    const int idx = b * 256 + threadIdx.x;
    const int m = idx >> 14;
    const int r = idx & 16383;
    const int n = r >> 7, k = r & 127;
    const float* W = (m == 0) ? Wsrc : (m == 1) ? Wtgt : (m == 2) ? Wskip : (m == 3) ? W1 : W2;
    const _Float16 hv = (_Float16)W[k * DIM + n];   // RNE scalar cvt
    Wall[idx] = *(const unsigned short*)&hv;
}

// ---------------------------------------------------------------------------
// Single-block scan, LDS-staged. rowptr only (scatter is atomic-free now).
// ---------------------------------------------------------------------------
__global__ __launch_bounds__(256) void scan_k(const int* __restrict__ deg,
                                              int* __restrict__ rowptr, int N)
{
    __shared__ int part[256];
    const int t = threadIdx.x;

    if (N <= NMAX) {
        __shared__ int s[NMAX];
        for (int k = t; k < N; k += 256) s[k] = deg[k];
        __syncthreads();

        const int chunk = (N + 255) / 256;
        const int lo = min(t * chunk, N), hi = min(lo + chunk, N);
        int sum = 0;
        for (int k = lo; k < hi; ++k) sum += s[k];
        part[t] = sum;
        __syncthreads();
        for (int off = 1; off < 256; off <<= 1) {
            int u = (t >= off) ? part[t - off] : 0;
            __syncthreads();
            part[t] += u;
            __syncthreads();
        }
        int run = part[t] - sum;
        for (int k = lo; k < hi; ++k) { const int d = s[k]; s[k] = run; run += d; }
        __syncthreads();
        for (int k = t; k < N; k += 256) rowptr[k] = s[k];
        if (t == 0) rowptr[N] = part[255];
    } else {
        const int chunk = (N + 255) / 256;
        const int lo = min(t * chunk, N), hi = min(lo + chunk, N);
        int s = 0;
        for (int k = lo; k < hi; ++k) s += deg[k];
        part[t] = s;
        __syncthreads();
        for (int off = 1; off < 256; off <<= 1) {
            int u = (t >= off) ? part[t - off] : 0;
            __syncthreads();
            part[t] += u;
            __syncthreads();
        }
        int run = part[t] - s;
        for (int k = lo; k < hi; ++k) {
            rowptr[k] = run;
            run += deg[k];
        }
        if (t == 255) rowptr[N] = part[255];
    }
}

// ---------------------------------------------------------------------------
// Merged scatter + node_linear. Scatter is atomic-free:
// p = rowptr[i] + rank[e] (rowptr L2-resident), fire-and-forget jip write.
// ---------------------------------------------------------------------------
__global__ __launch_bounds__(256) void scatter_node_k(
    const int* __restrict__ eidx, int E,
    const int* __restrict__ rowptr, const int* __restrict__ rank,
    int2* __restrict__ jip, int nscatter,
    const float* __restrict__ x,
    const unsigned short* __restrict__ Wall,
    const float* __restrict__ bsrc,
    unsigned short* __restrict__ msg_src, unsigned short* __restrict__ msg_tgt,
    float* __restrict__ skip, int N)
{
    if ((int)blockIdx.x < nscatter) {
        const int e = blockIdx.x * 256 + threadIdx.x;
        if (e < E) {
            const int j = eidx[e];
            const int i = eidx[(size_t)E + e];
            const int p = rowptr[i] + rank[e];
            jip[p] = make_int2(j, i);
        }
        return;
    }

    __shared__ unsigned short xt[32 * HSTR];
    const int t = threadIdx.x;
    const int n0blk = (blockIdx.x - nscatter) * 32;
    const int w = t >> 6, lane = t & 63, col = lane & 15, quad = lane >> 4;

    for (int k = t; k < 32 * 16; k += 256) {
        const int row = k >> 4, o = k & 15;
        uint4 v = make_uint4(0, 0, 0, 0);
        if (n0blk + row < N) {
            const float4 a = *(const float4*)(x + (size_t)(n0blk + row) * DIM + o * 8);
            const float4 b = *(const float4*)(x + (size_t)(n0blk + row) * DIM + o * 8 + 4);
            v.x = pkh(a.x, a.y); v.y = pkh(a.z, a.w);
            v.z = pkh(b.x, b.y); v.w = pkh(b.z, b.w);
        }
        *(uint4*)(xt + row * HSTR + o * 8) = v;
    }
    __syncthreads();

    hfrag af[2][4];
    #pragma unroll
    for (int mt = 0; mt < 2; ++mt)
        #pragma unroll
        for (int ks = 0; ks < 4; ++ks)
            af[mt][ks] = *(const hfrag*)(xt + (mt * 16 + col) * HSTR + ks * 32 + quad * 8);

    for (int m = 0; m < 3; ++m) {
        const unsigned short* Wt = Wall + m * DIM * DIM;
        hfrag bw[2][4];
        #pragma unroll
        for (int nt = 0; nt < 2; ++nt)
            #pragma unroll
            for (int ks = 0; ks < 4; ++ks)
                bw[nt][ks] = *(const hfrag*)(Wt + (w * 32 + nt * 16 + col) * DIM + ks * 32 + quad * 8);

        f32x4 acc[2][2];
        #pragma unroll
        for (int mt = 0; mt < 2; ++mt)
            #pragma unroll
            for (int nt = 0; nt < 2; ++nt)
                acc[mt][nt] = f32x4{0.f, 0.f, 0.f, 0.f};

        #pragma unroll
        for (int mt = 0; mt < 2; ++mt)
            #pragma unroll
            for (int nt = 0; nt < 2; ++nt)
                #pragma unroll
                for (int ks = 0; ks < 4; ++ks)
                    acc[mt][nt] = __builtin_amdgcn_mfma_f32_16x16x32_f16(
                        bw[nt][ks], af[mt][ks], acc[mt][nt], 0, 0, 0);

        #pragma unroll
        for (int mt = 0; mt < 2; ++mt) {
            const int node = n0blk + mt * 16 + col;
            if (node >= N) continue;
            #pragma unroll
            for (int nt = 0; nt < 2; ++nt) {
                const int f0 = w * 32 + nt * 16 + quad * 4;
                if (m == 2) {
                    float4 o;
                    o.x = acc[mt][nt][0]; o.y = acc[mt][nt][1];
                    o.z = acc[mt][nt][2]; o.w = acc[mt][nt][3];
                    *(float4*)(skip + (size_t)node * DIM + f0) = o;
                } else {
                    float b0 = 0.f, b1v = 0.f, b2v = 0.f, b3v = 0.f;
                    if (m == 0) {
                        const float4 bb = *(const float4*)(bsrc + f0);
                        b0 = bb.x; b1v = bb.y; b2v = bb.z; b3v = bb.w;
                    }
                    uint2 o;
                    o.x = pkh(acc[mt][nt][0] + b0, acc[mt][nt][1] + b1v);
                    o.y = pkh(acc[mt][nt][2] + b2v, acc[mt][nt][3] + b3v);
                    unsigned short* dst = (m == 0) ? msg_src : msg_tgt;
                    *(uint2*)(dst + (size_t)node * DIM + f0) = o;
                }
            }
        }
    }
}

// ---------------------------------------------------------------------------
// K2 (fused, node-partitioned): block b owns nodes [b*NPB, b*NPB+NPB).
// vs round 3: SINGLE h1 buffer. The existing two barriers already order a
// single buffer if the next-tile combine moves AFTER barrier B:
//   A | gather-issue(t+1) | GEMM1(reads h1) | epilogue(writes h2t/gate) |
//   B | combine(t+1 -> h1, reads done) | phase5(reads h2t/gate) | next A
// LDS drops 63.3 -> 45.9 KB => 3 blocks/CU (round-3 occupancy was the
// bottleneck: 2 blocks/CU, Occupancy 17.9%, HBM 5%, Mfma 9%).
// il_lds stays parity-buffered (phase5 needs current ids after combine).
// ---------------------------------------------------------------------------
__global__ __launch_bounds__(256, 3) void edge_fused_node(
    const int2* __restrict__ jip, const int* __restrict__ rowptr, int N,
    const unsigned short* __restrict__ msg_src, const unsigned short* __restrict__ msg_tgt,
    const float* __restrict__ a0p,
    const unsigned short* __restrict__ W1t, const float* __restrict__ b1,
    const float* __restrict__ a1p,
    const float* __restrict__ w2g,
    unsigned short* __restrict__ aggh2)
{
    __shared__ unsigned short h1[64 * HSTR];        // [edge][feat] for GEMM1 B (single)
    __shared__ unsigned short h2t[DIM * H2STR];     // [feat][edge] for MFMA2 A
    __shared__ float gate_part[4][64];
    __shared__ int il_lds[2][64];                   // per-edge target i (parity-buffered)
    __shared__ float S_lds[NPB][SSTR];              // fp32 weighted-sum accumulator
    __shared__ float Z_lds[NPB];

    const int t = threadIdx.x;
    const float a0 = *a0p, a1 = *a1p;
    const h2v a02 = {(_Float16)a0, (_Float16)a0};
    const int w = t >> 6, lane = t & 63, col = lane & 15, quad = lane >> 4;
    const int o = t & 15, r0 = t >> 4;

    const int n0 = blockIdx.x * NPB;
    const int elo = rowptr[n0];
    const int ehi = rowptr[min(n0 + NPB, N)];
    const int tc = (ehi - elo + 63) >> 6;           // local tile count

    // zero accumulators
    for (int k = t; k < NPB * SSTR; k += 256) ((float*)S_lds)[k] = 0.f;
    if (t < NPB) Z_lds[t] = 0.f;

    hfrag bw1[2][4];
    float4 b1q[2], wgq[2];
    #pragma unroll
    for (int nt = 0; nt < 2; ++nt) {
        const int n = w * 32 + nt * 16 + col;
        #pragma unroll
        for (int ks = 0; ks < 4; ++ks)
            bw1[nt][ks] = *(const hfrag*)(W1t + n * DIM + ks * 32 + quad * 8);
        const int nq = w * 32 + nt * 16 + quad * 4;
        b1q[nt] = *(const float4*)(b1 + nq);
        wgq[nt] = *(const float4*)(w2g + nq);
    }
    const float c2 = w2g[DIM];

    if (tc > 0) {
        // prologue: gather+combine tile 0 into h1; prefetch tile-1 idx
        {
            int2 e0r[4];
            #pragma unroll
            for (int i = 0; i < 4; ++i)
                e0r[i] = jip[min(elo + r0 + 16 * i, ehi - 1)];
            #pragma unroll
            for (int i = 0; i < 4; ++i) {
                const uint4 sv = *(const uint4*)(msg_src + (size_t)e0r[i].x * DIM + o * 8);
                const uint4 gv = *(const uint4*)(msg_tgt + (size_t)e0r[i].y * DIM + o * 8);
                uint4 hv;
                hv.x = prelu2_add(sv.x, gv.x, a02);
                hv.y = prelu2_add(sv.y, gv.y, a02);
                hv.z = prelu2_add(sv.z, gv.z, a02);
                hv.w = prelu2_add(sv.w, gv.w, a02);
                *(uint4*)(h1 + (r0 + 16 * i) * HSTR + o * 8) = hv;
                if (o == 0) il_lds[0][r0 + 16 * i] = e0r[i].y;
            }
        }
        int2 eN[4];
        {
            const int t1 = min(1, tc - 1);
            #pragma unroll
            for (int i = 0; i < 4; ++i)
                eN[i] = jip[min(elo + t1 * 64 + r0 + 16 * i, ehi - 1)];
        }

        int par = 0;

        for (int tt = 0; tt < tc; ++tt) {
            __syncthreads();   // A: h1+il[par] visible; prev phase-5 h2t/gate reads done

            const bool pf = (tt + 1 < tc);

            // 1. issue NEXT tile's gathers (latency hidden under GEMM1 below)
            uint4 sv[4], gv[4];
            if (pf) {
                #pragma unroll
                for (int i = 0; i < 4; ++i) {
                    sv[i] = *(const uint4*)(msg_src + (size_t)eN[i].x * DIM + o * 8);
                    gv[i] = *(const uint4*)(msg_tgt + (size_t)eN[i].y * DIM + o * 8);
                }
            }
            // idx prefetch for tile tt+2 (sequential, cheap)
            int2 eP[4];
            {
                const int t2 = min(tt + 2, tc - 1);
                #pragma unroll
                for (int i = 0; i < 4; ++i)
                    eP[i] = jip[min(elo + t2 * 64 + r0 + 16 * i, ehi - 1)];
            }

            // 2. GEMM1 (transposed, fp16) from h1
            f32x4 acc[4][2];
            #pragma unroll
            for (int mt = 0; mt < 4; ++mt)
                #pragma unroll
                for (int nt = 0; nt < 2; ++nt)
                    acc[mt][nt] = f32x4{0.f, 0.f, 0.f, 0.f};

            __builtin_amdgcn_s_setprio(1);
            #pragma unroll
            for (int mt = 0; mt < 4; ++mt) {
                hfrag af[4];
                #pragma unroll
                for (int ks = 0; ks < 4; ++ks)
                    af[ks] = *(const hfrag*)(h1 + (mt * 16 + col) * HSTR + ks * 32 + quad * 8);
                #pragma unroll
                for (int nt = 0; nt < 2; ++nt)
                    #pragma unroll
                    for (int ks = 0; ks < 4; ++ks)
                        acc[mt][nt] = __builtin_amdgcn_mfma_f32_16x16x32_f16(
                            bw1[nt][ks], af[ks], acc[mt][nt], 0, 0, 0);
            }
            __builtin_amdgcn_s_setprio(0);

            // 3. epilogue: prelu -> h2t (fp16, [feat][edge]), gate partials
            #pragma unroll
            for (int mt = 0; mt < 4; ++mt) {
                const int m = mt * 16 + col;
                float g = 0.f;
                #pragma unroll
                for (int nt = 0; nt < 2; ++nt) {
                    const int fb = w * 32 + nt * 16 + quad * 4;
                    const float p0v = prelu_f(acc[mt][nt][0] + b1q[nt].x, a1);
                    const float p1v = prelu_f(acc[mt][nt][1] + b1q[nt].y, a1);
                    const float p2v = prelu_f(acc[mt][nt][2] + b1q[nt].z, a1);
                    const float p3v = prelu_f(acc[mt][nt][3] + b1q[nt].w, a1);
                    h2t[(fb + 0) * H2STR + m] = hs(p0v);
                    h2t[(fb + 1) * H2STR + m] = hs(p1v);
                    h2t[(fb + 2) * H2STR + m] = hs(p2v);
                    h2t[(fb + 3) * H2STR + m] = hs(p3v);
                    g += p0v * wgq[nt].x + p1v * wgq[nt].y + p2v * wgq[nt].z + p3v * wgq[nt].w;
                }
                g += __shfl_xor(g, 16);
                g += __shfl_xor(g, 32);
                if (quad == 0) gate_part[w][m] = g;
            }

            __syncthreads();   // B: h2t + gate_part visible; all h1 reads done

            // 4. combine NEXT tile into h1 (safe: reads drained at B)
            if (pf) {
                #pragma unroll
                for (int i = 0; i < 4; ++i) {
                    uint4 hv;
                    hv.x = prelu2_add(sv[i].x, gv[i].x, a02);
                    hv.y = prelu2_add(sv[i].y, gv[i].y, a02);
                    hv.z = prelu2_add(sv[i].z, gv[i].z, a02);
                    hv.w = prelu2_add(sv[i].w, gv[i].w, a02);
                    *(uint4*)(h1 + (r0 + 16 * i) * HSTR + o * 8) = hv;
                    if (o == 0) il_lds[par ^ 1][r0 + 16 * i] = eN[i].y;
                }
                #pragma unroll
                for (int i = 0; i < 4; ++i) eN[i] = eP[i];
            }

            // 5. softmax weights + reduction-MFMA + LDS accumulate
            {
                const int ebase = elo + tt * 64;
                const int limit = min(64, ehi - ebase);   // valid edges in this tile
                const int i0v = il_lds[par][0];
                const int span = il_lds[par][63] - i0v;   // <= NPB-1 by construction
                for (int nl0 = 0; nl0 <= span; nl0 += 16) {
                    const int nbase = i0v + nl0;
                    const int nrelb = nbase - n0;
                    const int rem = span - nl0;           // last valid local node col
                    hfrag bf2[2];
                    float zp = 0.f;
                    #pragma unroll
                    for (int ks = 0; ks < 2; ++ks) {
                        const int e0 = ks * 32 + quad * 8;
                        const float4 ga0 = *(const float4*)&gate_part[0][e0];
                        const float4 ga1 = *(const float4*)&gate_part[1][e0];
                        const float4 ga2 = *(const float4*)&gate_part[2][e0];
                        const float4 ga3 = *(const float4*)&gate_part[3][e0];
                        const float4 gb0 = *(const float4*)&gate_part[0][e0 + 4];
                        const float4 gb1 = *(const float4*)&gate_part[1][e0 + 4];
                        const float4 gb2 = *(const float4*)&gate_part[2][e0 + 4];
                        const float4 gb3 = *(const float4*)&gate_part[3][e0 + 4];
                        const int4 ia = *(const int4*)&il_lds[par][e0];
                        const int4 ib = *(const int4*)&il_lds[par][e0 + 4];
                        // e = exp(min(gate, 11)): fp16-safe (e^11 < 65504)
                        const float e0v = __expf(fminf(ga0.x + ga1.x + ga2.x + ga3.x + c2, 11.f));
                        const float e1v = __expf(fminf(ga0.y + ga1.y + ga2.y + ga3.y + c2, 11.f));
                        const float e2v = __expf(fminf(ga0.z + ga1.z + ga2.z + ga3.z + c2, 11.f));
                        const float e3v = __expf(fminf(ga0.w + ga1.w + ga2.w + ga3.w + c2, 11.f));
                        const float e4v = __expf(fminf(gb0.x + gb1.x + gb2.x + gb3.x + c2, 11.f));
                        const float e5v = __expf(fminf(gb0.y + gb1.y + gb2.y + gb3.y + c2, 11.f));
                        const float e6v = __expf(fminf(gb0.z + gb1.z + gb2.z + gb3.z + c2, 11.f));
                        const float e7v = __expf(fminf(gb0.w + gb1.w + gb2.w + gb3.w + c2, 11.f));
                        // select node column; mask padded tail edges to 0
                        const float s0 = (ia.x - nbase == col && e0 + 0 < limit) ? e0v : 0.f;
                        const float s1 = (ia.y - nbase == col && e0 + 1 < limit) ? e1v : 0.f;
                        const float s2 = (ia.z - nbase == col && e0 + 2 < limit) ? e2v : 0.f;
                        const float s3 = (ia.w - nbase == col && e0 + 3 < limit) ? e3v : 0.f;
                        const float s4 = (ib.x - nbase == col && e0 + 4 < limit) ? e4v : 0.f;
                        const float s5 = (ib.y - nbase == col && e0 + 5 < limit) ? e5v : 0.f;
                        const float s6 = (ib.z - nbase == col && e0 + 6 < limit) ? e6v : 0.f;
                        const float s7 = (ib.w - nbase == col && e0 + 7 < limit) ? e7v : 0.f;
                        zp += s0 + s1 + s2 + s3 + s4 + s5 + s6 + s7;
                        uint4 uu;
                        uu.x = pkh(s0, s1); uu.y = pkh(s2, s3);
                        uu.z = pkh(s4, s5); uu.w = pkh(s6, s7);
                        bf2[ks] = *(hfrag*)&uu;
                    }
                    // Z partial: sum E column over k (quad reduce), one wave adds
                    float z = zp;
                    z += __shfl_xor(z, 16);
                    z += __shfl_xor(z, 32);
                    if (w == 0 && quad == 0 && col <= rem)
                        Z_lds[nrelb + col] += z;
                    // reduction MFMA: D[f_local][node_local] -> S_lds
                    #pragma unroll
                    for (int nt = 0; nt < 2; ++nt) {
                        f32x4 r2 = f32x4{0.f, 0.f, 0.f, 0.f};
                        #pragma unroll
                        for (int ks = 0; ks < 2; ++ks) {
                            const hfrag a2 = *(const hfrag*)(
                                h2t + (w * 32 + nt * 16 + col) * H2STR + ks * 32 + quad * 8);
                            r2 = __builtin_amdgcn_mfma_f32_16x16x32_f16(a2, bf2[ks], r2, 0, 0, 0);
                        }
                        if (col <= rem) {
                            float* dst = &S_lds[nrelb + col][w * 32 + nt * 16 + quad * 4];
                            dst[0] += r2[0];
                            dst[1] += r2[1];
                            dst[2] += r2[2];
                            dst[3] += r2[3];
                        }
                    }
                }
            }

            par ^= 1;
        }
    }

    __syncthreads();   // all phase-5 accumulates done

    // epilogue: aggh2[n] = fp16(S/Z) for the block's NPB nodes
    for (int k = t; k < NPB * 16; k += 256) {
        const int nr = k >> 4, oo = k & 15;
        const int node = n0 + nr;
        if (node < N) {
            const float invz = 1.f / (Z_lds[nr] + 1e-16f);
            const float* src = &S_lds[nr][oo * 8];
            uint4 ov;
            ov.x = pkh(src[0] * invz, src[1] * invz);
            ov.y = pkh(src[2] * invz, src[3] * invz);
            ov.z = pkh(src[4] * invz, src[5] * invz);
            ov.w = pkh(src[6] * invz, src[7] * invz);
            *(uint4*)(aggh2 + (size_t)node * DIM + oo * 8) = ov;
        }
    }
}

// ---------------------------------------------------------------------------
// K4: out = LN(aggh2 @ W2 + b2 + skip) * gamma + beta, via fp16 MFMA.
// ---------------------------------------------------------------------------
__global__ __launch_bounds__(256) void node_out_k(
    const unsigned short* __restrict__ aggh2,
    const unsigned short* __restrict__ W2t, const float* __restrict__ b2,
    const float* __restrict__ skip,
    const float* __restrict__ gamma, const float* __restrict__ beta,
    float* __restrict__ out, int N)
{
    __shared__ unsigned short hh[64 * HSTR];
    __shared__ float ls1[4][4][16], ls2[4][4][16];

    const int t = threadIdx.x;
    const int n0blk = blockIdx.x * 64;
    const int w = t >> 6, lane = t & 63, col = lane & 15, quad = lane >> 4;

    hfrag bw2[2][4];
    float4 b2q[2];
    #pragma unroll
    for (int nt = 0; nt < 2; ++nt) {
        const int n = w * 32 + nt * 16 + col;
        #pragma unroll
        for (int ks = 0; ks < 4; ++ks)
            bw2[nt][ks] = *(const hfrag*)(W2t + n * DIM + ks * 32 + quad * 8);
        b2q[nt] = *(const float4*)(b2 + w * 32 + nt * 16 + quad * 4);
    }

    for (int k = t; k < 64 * 16; k += 256) {
        const int row = k >> 4, oo = k & 15;
        uint4 v = make_uint4(0, 0, 0, 0);
        if (n0blk + row < N) v = *(const uint4*)(aggh2 + (size_t)(n0blk + row) * DIM + oo * 8);
        *(uint4*)(hh + row * HSTR + oo * 8) = v;
    }
    __syncthreads();

    f32x4 acc[4][2];
    #pragma unroll
    for (int mt = 0; mt < 4; ++mt)
        #pragma unroll
        for (int nt = 0; nt < 2; ++nt)
            acc[mt][nt] = f32x4{0.f, 0.f, 0.f, 0.f};

    #pragma unroll
    for (int mt = 0; mt < 4; ++mt) {
        hfrag af[4];
        #pragma unroll
        for (int ks = 0; ks < 4; ++ks)
            af[ks] = *(const hfrag*)(hh + (mt * 16 + col) * HSTR + ks * 32 + quad * 8);
        #pragma unroll
        for (int nt = 0; nt < 2; ++nt)
            #pragma unroll
            for (int ks = 0; ks < 4; ++ks)
                acc[mt][nt] = __builtin_amdgcn_mfma_f32_16x16x32_f16(
                    bw2[nt][ks], af[ks], acc[mt][nt], 0, 0, 0);
    }

    float v[4][2][4];
    #pragma unroll
    for (int mt = 0; mt < 4; ++mt) {
        const int node = n0blk + mt * 16 + col;
        float s1 = 0.f, s2 = 0.f;
        #pragma unroll
        for (int nt = 0; nt < 2; ++nt) {
            const int f0 = w * 32 + nt * 16 + quad * 4;
            float4 sk = make_float4(0.f, 0.f, 0.f, 0.f);
            if (node < N) sk = *(const float4*)(skip + (size_t)node * DIM + f0);
            v[mt][nt][0] = acc[mt][nt][0] + b2q[nt].x + sk.x;
            v[mt][nt][1] = acc[mt][nt][1] + b2q[nt].y + sk.y;
            v[mt][nt][2] = acc[mt][nt][2] + b2q[nt].z + sk.z;
            v[mt][nt][3] = acc[mt][nt][3] + b2q[nt].w + sk.w;
            #pragma unroll
            for (int r = 0; r < 4; ++r) {
                s1 += v[mt][nt][r];
                s2 += v[mt][nt][r] * v[mt][nt][r];
            }
        }
        s1 += __shfl_xor(s1, 16); s1 += __shfl_xor(s1, 32);
        s2 += __shfl_xor(s2, 16); s2 += __shfl_xor(s2, 32);
        if (quad == 0) { ls1[w][mt][col] = s1; ls2[w][mt][col] = s2; }
    }
    __syncthreads();

    #pragma unroll
    for (int mt = 0; mt < 4; ++mt) {
        const int node = n0blk + mt * 16 + col;
        if (node >= N) continue;
        const float sum = ls1[0][mt][col] + ls1[1][mt][col] + ls1[2][mt][col] + ls1[3][mt][col];
        const float sq  = ls2[0][mt][col] + ls2[1][mt][col] + ls2[2][mt][col] + ls2[3][mt][col];
        const float mu = sum * (1.f / 128.f);
        const float var = sq * (1.f / 128.f) - mu * mu;
        const float rs = rsqrtf(var + 1e-5f);
        #pragma unroll
        for (int nt = 0; nt < 2; ++nt) {
            const int f0 = w * 32 + nt * 16 + quad * 4;
            const float4 gm = *(const float4*)(gamma + f0);
            const float4 bt = *(const float4*)(beta + f0);
            float4 ov;
            ov.x = (v[mt][nt][0] - mu) * rs * gm.x + bt.x;
            ov.y = (v[mt][nt][1] - mu) * rs * gm.y + bt.y;
            ov.z = (v[mt][nt][2] - mu) * rs * gm.z + bt.z;
            ov.w = (v[mt][nt][3] - mu) * rs * gm.w + bt.w;
            *(float4*)(out + (size_t)node * DIM + f0) = ov;
        }
    }
}

// ---------------------------------------------------------------------------
extern "C" void kernel_launch(void* const* d_in, const int* in_sizes, int n_in,
                              void* d_out, int out_size, void* d_ws, size_t ws_size,
                              hipStream_t stream)
{
    const float* x     = (const float*)d_in[0];
    const int*   eidx  = (const int*)d_in[1];
    const float* Wsrc  = (const float*)d_in[2];
    const float* bsrc  = (const float*)d_in[3];
    const float* Wtgt  = (const float*)d_in[4];
    const float* Wskip = (const float*)d_in[5];
    const float* a0    = (const float*)d_in[6];
    const float* W1    = (const float*)d_in[7];
    const float* b1    = (const float*)d_in[8];
    const float* a1    = (const float*)d_in[9];
    const float* W2    = (const float*)d_in[10];
    const float* b2    = (const float*)d_in[11];
    const float* Wg    = (const float*)d_in[12];
    const float* gamma = (const float*)d_in[13];
    const float* beta  = (const float*)d_in[14];

    const int N = in_sizes[0] / DIM;      // 20000
    const int E = in_sizes[1] / 2;        // 640000
    const int Npad = ((N + 63) / 64) * 64;
    float* out = (float*)d_out;

    char* ws = (char*)d_ws;
    size_t off = 0;
    auto alloc = [&](size_t bytes) -> void* {
        void* p = ws + off;
        off += (bytes + 255) & ~(size_t)255;
        return p;
    };
    int*            deg     = (int*)alloc((size_t)N * 4);
    unsigned short* msg_src = (unsigned short*)alloc((size_t)N * DIM * 2);
    unsigned short* msg_tgt = (unsigned short*)alloc((size_t)N * DIM * 2);
    float*          skip    = (float*)alloc((size_t)N * DIM * 4);
    int*            rowptr  = (int*)alloc((size_t)(N + 1) * 4);
    int*            rank    = (int*)alloc((size_t)E * 4);
    int2*           jip     = (int2*)alloc((size_t)E * 8);
    unsigned short* Wall    = (unsigned short*)alloc((size_t)5 * DIM * DIM * 2);
    float*          w2g     = (float*)alloc((size_t)(DIM + 1) * 4);
    unsigned short* aggh2   = (unsigned short*)alloc((size_t)Npad * DIM * 2);
    (void)ws_size; (void)n_in; (void)out_size;

    (void)hipMemsetAsync(deg, 0, (size_t)N * 4, stream);

    const int nhist = (E + 255) / 256;
    prep_hist_k<<<nhist + (5 * DIM * DIM) / 256 + 1, 256, 0, stream>>>(
        Wsrc, Wtgt, Wskip, W1, W2, b2, Wg, Wall, w2g, eidx, E, deg, rank);

    scan_k<<<1, 256, 0, stream>>>(deg, rowptr, N);

    const int nscatter = (E + 255) / 256;
    const int nnode = (N + 31) / 32;
    scatter_node_k<<<nscatter + nnode, 256, 0, stream>>>(
        eidx, E, rowptr, rank, jip, nscatter,
        x, Wall, bsrc, msg_src, msg_tgt, skip, N);

    const int nblk = (N + NPB - 1) / NPB;
    edge_fused_node<<<nblk, 256, 0, stream>>>(jip, rowptr, N, msg_src, msg_tgt, a0,
                                              Wall + 3 * DIM * DIM, b1, a1,
                                              w2g, aggh2);

    node_out_k<<<Npad / 64, 256, 0, stream>>>(aggh2, Wall + 4 * DIM * DIM, b2, skip,
                                              gamma, beta, out, N);
}

// Round 5
// 251.130 us; speedup vs baseline: 1.1030x; 1.1030x over previous
//
#include <hip/hip_runtime.h>
#include <hip/hip_bf16.h>
#include <stdint.h>

// Problem constants (reference: N=20000, E=640000, C=D=M=128)
#define DIM 128
#define HSTR 136    // padded LDS row stride in fp16 elems (272 B, 16B-aligned rows)
#define H2STR 72    // h2t row stride in fp16 elems (144 B, 16B-aligned rows)
#define NPB 16      // nodes per block == MFMA N dim (enables register-S accumulate)
#define NMAX 20224  // LDS-staged scan capacity

using hfrag = __attribute__((ext_vector_type(8))) _Float16;  // 8 fp16 (4 VGPRs)
using h2v   = __attribute__((ext_vector_type(2))) _Float16;
using f32x4 = __attribute__((ext_vector_type(4))) float;     // MFMA C/D

__device__ __forceinline__ float prelu_f(float v, float a) { return v >= 0.f ? v : a * v; }

// pack 2 floats -> fp16x2 (RTZ, 1 inst). Builtin returns __fp16x2; bitcast.
__device__ __forceinline__ unsigned pkh(float a, float b) {
    auto h = __builtin_amdgcn_cvt_pkrtz(a, b);
    return *(unsigned*)&h;
}
__device__ __forceinline__ unsigned short hs(float v) {
    _Float16 h = (_Float16)v;
    return *(unsigned short*)&h;
}
// packed fp16 prelu of (s+g): min(h,0)*a + max(h,0)
__device__ __forceinline__ unsigned prelu2_add(unsigned su, unsigned gu, h2v a2) {
    h2v s = *(h2v*)&su, g = *(h2v*)&gu;
    h2v h = s + g;
    h2v z = {(_Float16)0.f, (_Float16)0.f};
    h2v mx = __builtin_elementwise_max(h, z);
    h2v mn = __builtin_elementwise_min(h, z);
    h2v r = mn * a2 + mx;
    return *(unsigned*)&r;
}

// ---------------------------------------------------------------------------
// Merged prep + hist. Hist also captures per-edge rank (coalesced store),
// so the later scatter needs NO atomics. Wall[m][n][k] = fp16(W_m[k][n]).
// ---------------------------------------------------------------------------
__global__ __launch_bounds__(256) void prep_hist_k(
    const float* __restrict__ Wsrc, const float* __restrict__ Wtgt,
    const float* __restrict__ Wskip, const float* __restrict__ W1,
    const float* __restrict__ W2, const float* __restrict__ b2,
    const float* __restrict__ Wg,
    unsigned short* __restrict__ Wall, float* __restrict__ w2g,
    const int* __restrict__ eidx, int E, int* __restrict__ deg,
    int* __restrict__ rank)
{
    const int nhist = (E + 255) / 256;
    if ((int)blockIdx.x < nhist) {
        const int e = blockIdx.x * 256 + threadIdx.x;
        if (e < E) rank[e] = atomicAdd(deg + eidx[(size_t)E + e], 1);
        return;
    }
    const int b = blockIdx.x - nhist;
    if (b == (5 * DIM * DIM) / 256) {   // w2g block
        const int k = threadIdx.x;
        if (k < DIM) {
            float s = 0.f;
            for (int d = 0; d < DIM; ++d) s += W2[k * DIM + d] * Wg[d];
            w2g[k] = s;
        } else if (k == DIM) {
            float s = 0.f;
            for (int d = 0; d < DIM; ++d) s += b2[d] * Wg[d];
            w2g[DIM] = s;
        }
        return;
    }
    const int idx = b * 256 + threadIdx.x;
    const int m = idx >> 14;
    const int r = idx & 16383;
    const int n = r >> 7, k = r & 127;
    const float* W = (m == 0) ? Wsrc : (m == 1) ? Wtgt : (m == 2) ? Wskip : (m == 3) ? W1 : W2;
    const _Float16 hv = (_Float16)W[k * DIM + n];   // RNE scalar cvt
    Wall[idx] = *(const unsigned short*)&hv;
}

// ---------------------------------------------------------------------------
// Single-block scan, LDS-staged. rowptr only (scatter is atomic-free now).
// ---------------------------------------------------------------------------
__global__ __launch_bounds__(256) void scan_k(const int* __restrict__ deg,
                                              int* __restrict__ rowptr, int N)
{
    __shared__ int part[256];
    const int t = threadIdx.x;

    if (N <= NMAX) {
        __shared__ int s[NMAX];
        for (int k = t; k < N; k += 256) s[k] = deg[k];
        __syncthreads();

        const int chunk = (N + 255) / 256;
        const int lo = min(t * chunk, N), hi = min(lo + chunk, N);
        int sum = 0;
        for (int k = lo; k < hi; ++k) sum += s[k];
        part[t] = sum;
        __syncthreads();
        for (int off = 1; off < 256; off <<= 1) {
            int u = (t >= off) ? part[t - off] : 0;
            __syncthreads();
            part[t] += u;
            __syncthreads();
        }
        int run = part[t] - sum;
        for (int k = lo; k < hi; ++k) { const int d = s[k]; s[k] = run; run += d; }
        __syncthreads();
        for (int k = t; k < N; k += 256) rowptr[k] = s[k];
        if (t == 0) rowptr[N] = part[255];
    } else {
        const int chunk = (N + 255) / 256;
        const int lo = min(t * chunk, N), hi = min(lo + chunk, N);
        int s = 0;
        for (int k = lo; k < hi; ++k) s += deg[k];
        part[t] = s;
        __syncthreads();
        for (int off = 1; off < 256; off <<= 1) {
            int u = (t >= off) ? part[t - off] : 0;
            __syncthreads();
            part[t] += u;
            __syncthreads();
        }
        int run = part[t] - s;
        for (int k = lo; k < hi; ++k) {
            rowptr[k] = run;
            run += deg[k];
        }
        if (t == 255) rowptr[N] = part[255];
    }
}

// ---------------------------------------------------------------------------
// Merged scatter + node_linear. Scatter is atomic-free:
// p = rowptr[i] + rank[e] (rowptr L2-resident), fire-and-forget jip write.
// ---------------------------------------------------------------------------
__global__ __launch_bounds__(256) void scatter_node_k(
    const int* __restrict__ eidx, int E,
    const int* __restrict__ rowptr, const int* __restrict__ rank,
    int2* __restrict__ jip, int nscatter,
    const float* __restrict__ x,
    const unsigned short* __restrict__ Wall,
    const float* __restrict__ bsrc,
    unsigned short* __restrict__ msg_src, unsigned short* __restrict__ msg_tgt,
    float* __restrict__ skip, int N)
{
    if ((int)blockIdx.x < nscatter) {
        const int e = blockIdx.x * 256 + threadIdx.x;
        if (e < E) {
            const int j = eidx[e];
            const int i = eidx[(size_t)E + e];
            const int p = rowptr[i] + rank[e];
            jip[p] = make_int2(j, i);
        }
        return;
    }

    __shared__ unsigned short xt[32 * HSTR];
    const int t = threadIdx.x;
    const int n0blk = (blockIdx.x - nscatter) * 32;
    const int w = t >> 6, lane = t & 63, col = lane & 15, quad = lane >> 4;

    for (int k = t; k < 32 * 16; k += 256) {
        const int row = k >> 4, o = k & 15;
        uint4 v = make_uint4(0, 0, 0, 0);
        if (n0blk + row < N) {
            const float4 a = *(const float4*)(x + (size_t)(n0blk + row) * DIM + o * 8);
            const float4 b = *(const float4*)(x + (size_t)(n0blk + row) * DIM + o * 8 + 4);
            v.x = pkh(a.x, a.y); v.y = pkh(a.z, a.w);
            v.z = pkh(b.x, b.y); v.w = pkh(b.z, b.w);
        }
        *(uint4*)(xt + row * HSTR + o * 8) = v;
    }
    __syncthreads();

    hfrag af[2][4];
    #pragma unroll
    for (int mt = 0; mt < 2; ++mt)
        #pragma unroll
        for (int ks = 0; ks < 4; ++ks)
            af[mt][ks] = *(const hfrag*)(xt + (mt * 16 + col) * HSTR + ks * 32 + quad * 8);

    for (int m = 0; m < 3; ++m) {
        const unsigned short* Wt = Wall + m * DIM * DIM;
        hfrag bw[2][4];
        #pragma unroll
        for (int nt = 0; nt < 2; ++nt)
            #pragma unroll
            for (int ks = 0; ks < 4; ++ks)
                bw[nt][ks] = *(const hfrag*)(Wt + (w * 32 + nt * 16 + col) * DIM + ks * 32 + quad * 8);

        f32x4 acc[2][2];
        #pragma unroll
        for (int mt = 0; mt < 2; ++mt)
            #pragma unroll
            for (int nt = 0; nt < 2; ++nt)
                acc[mt][nt] = f32x4{0.f, 0.f, 0.f, 0.f};

        #pragma unroll
        for (int mt = 0; mt < 2; ++mt)
            #pragma unroll
            for (int nt = 0; nt < 2; ++nt)
                #pragma unroll
                for (int ks = 0; ks < 4; ++ks)
                    acc[mt][nt] = __builtin_amdgcn_mfma_f32_16x16x32_f16(
                        bw[nt][ks], af[mt][ks], acc[mt][nt], 0, 0, 0);

        #pragma unroll
        for (int mt = 0; mt < 2; ++mt) {
            const int node = n0blk + mt * 16 + col;
            if (node >= N) continue;
            #pragma unroll
            for (int nt = 0; nt < 2; ++nt) {
                const int f0 = w * 32 + nt * 16 + quad * 4;
                if (m == 2) {
                    float4 o;
                    o.x = acc[mt][nt][0]; o.y = acc[mt][nt][1];
                    o.z = acc[mt][nt][2]; o.w = acc[mt][nt][3];
                    *(float4*)(skip + (size_t)node * DIM + f0) = o;
                } else {
                    float b0 = 0.f, b1v = 0.f, b2v = 0.f, b3v = 0.f;
                    if (m == 0) {
                        const float4 bb = *(const float4*)(bsrc + f0);
                        b0 = bb.x; b1v = bb.y; b2v = bb.z; b3v = bb.w;
                    }
                    uint2 o;
                    o.x = pkh(acc[mt][nt][0] + b0, acc[mt][nt][1] + b1v);
                    o.y = pkh(acc[mt][nt][2] + b2v, acc[mt][nt][3] + b3v);
                    unsigned short* dst = (m == 0) ? msg_src : msg_tgt;
                    *(uint2*)(dst + (size_t)node * DIM + f0) = o;
                }
            }
        }
    }
}

// ---------------------------------------------------------------------------
// K2 (fused, node-partitioned): block b owns nodes [b*NPB, b*NPB+NPB).
// NPB == 16 == MFMA N dim, so the reduction MFMA's E-matrix columns are
// pinned to the block's 16 nodes and S accumulates IN THE MFMA C REGISTERS
// across all tiles (acc2[nt] = mfma(a2, bf2, acc2[nt])). No S_lds, no Z_lds,
// no nl0/span logic; Z is a register (z identical across quads/waves after
// the shfl reduce). LDS = 37.4 KB. launch_bounds(256,2): (256,3) reliably
// triggers an 84-VGPR + scratch-spill allocation (rounds 2,4 — 77/22 MB
// phantom WRITE_SIZE); (256,2) gives ~100-150 VGPR, no spill (round 3).
// ---------------------------------------------------------------------------
__global__ __launch_bounds__(256, 2) void edge_fused_node(
    const int2* __restrict__ jip, const int* __restrict__ rowptr, int N,
    const unsigned short* __restrict__ msg_src, const unsigned short* __restrict__ msg_tgt,
    const float* __restrict__ a0p,
    const unsigned short* __restrict__ W1t, const float* __restrict__ b1,
    const float* __restrict__ a1p,
    const float* __restrict__ w2g,
    unsigned short* __restrict__ aggh2)
{
    __shared__ unsigned short h1[64 * HSTR];        // [edge][feat] for GEMM1 B (single)
    __shared__ unsigned short h2t[DIM * H2STR];     // [feat][edge] for MFMA2 A
    __shared__ float gate_part[4][64];
    __shared__ int il_lds[2][64];                   // per-edge target i (parity-buffered)

    const int t = threadIdx.x;
    const float a0 = *a0p, a1 = *a1p;
    const h2v a02 = {(_Float16)a0, (_Float16)a0};
    const int w = t >> 6, lane = t & 63, col = lane & 15, quad = lane >> 4;
    const int o = t & 15, r0 = t >> 4;

    const int n0 = blockIdx.x * NPB;
    const int elo = rowptr[n0];
    const int ehi = rowptr[min(n0 + NPB, N)];
    const int tc = (ehi - elo + 63) >> 6;           // local tile count

    hfrag bw1[2][4];
    float4 b1q[2], wgq[2];
    #pragma unroll
    for (int nt = 0; nt < 2; ++nt) {
        const int n = w * 32 + nt * 16 + col;
        #pragma unroll
        for (int ks = 0; ks < 4; ++ks)
            bw1[nt][ks] = *(const hfrag*)(W1t + n * DIM + ks * 32 + quad * 8);
        const int nq = w * 32 + nt * 16 + quad * 4;
        b1q[nt] = *(const float4*)(b1 + nq);
        wgq[nt] = *(const float4*)(w2g + nq);
    }
    const float c2 = w2g[DIM];

    // persistent per-thread accumulators: S[node=col][feat slice] and Z[col]
    f32x4 acc2[2] = {f32x4{0.f, 0.f, 0.f, 0.f}, f32x4{0.f, 0.f, 0.f, 0.f}};
    float zreg = 0.f;

    if (tc > 0) {
        // prologue: gather+combine tile 0 into h1; prefetch tile-1 idx
        {
            int2 e0r[4];
            #pragma unroll
            for (int i = 0; i < 4; ++i)
                e0r[i] = jip[min(elo + r0 + 16 * i, ehi - 1)];
            #pragma unroll
            for (int i = 0; i < 4; ++i) {
                const uint4 sv = *(const uint4*)(msg_src + (size_t)e0r[i].x * DIM + o * 8);
                const uint4 gv = *(const uint4*)(msg_tgt + (size_t)e0r[i].y * DIM + o * 8);
                uint4 hv;
                hv.x = prelu2_add(sv.x, gv.x, a02);
                hv.y = prelu2_add(sv.y, gv.y, a02);
                hv.z = prelu2_add(sv.z, gv.z, a02);
                hv.w = prelu2_add(sv.w, gv.w, a02);
                *(uint4*)(h1 + (r0 + 16 * i) * HSTR + o * 8) = hv;
                if (o == 0) il_lds[0][r0 + 16 * i] = e0r[i].y;
            }
        }
        int2 eN[4];
        {
            const int t1 = min(1, tc - 1);
            #pragma unroll
            for (int i = 0; i < 4; ++i)
                eN[i] = jip[min(elo + t1 * 64 + r0 + 16 * i, ehi - 1)];
        }

        int par = 0;

        for (int tt = 0; tt < tc; ++tt) {
            __syncthreads();   // A: h1+il[par] visible; prev phase-5 h2t/gate reads done

            const bool pf = (tt + 1 < tc);

            // 1. issue NEXT tile's gathers (latency hidden under GEMM1 below)
            uint4 sv[4], gv[4];
            if (pf) {
                #pragma unroll
                for (int i = 0; i < 4; ++i) {
                    sv[i] = *(const uint4*)(msg_src + (size_t)eN[i].x * DIM + o * 8);
                    gv[i] = *(const uint4*)(msg_tgt + (size_t)eN[i].y * DIM + o * 8);
                }
            }

            // 2. GEMM1 (transposed, fp16) from h1
            f32x4 acc[4][2];
            #pragma unroll
            for (int mt = 0; mt < 4; ++mt)
                #pragma unroll
                for (int nt = 0; nt < 2; ++nt)
                    acc[mt][nt] = f32x4{0.f, 0.f, 0.f, 0.f};

            __builtin_amdgcn_s_setprio(1);
            #pragma unroll
            for (int mt = 0; mt < 4; ++mt) {
                hfrag af[4];
                #pragma unroll
                for (int ks = 0; ks < 4; ++ks)
                    af[ks] = *(const hfrag*)(h1 + (mt * 16 + col) * HSTR + ks * 32 + quad * 8);
                #pragma unroll
                for (int nt = 0; nt < 2; ++nt)
                    #pragma unroll
                    for (int ks = 0; ks < 4; ++ks)
                        acc[mt][nt] = __builtin_amdgcn_mfma_f32_16x16x32_f16(
                            bw1[nt][ks], af[ks], acc[mt][nt], 0, 0, 0);
            }
            __builtin_amdgcn_s_setprio(0);

            // 3. epilogue: prelu -> h2t (fp16, [feat][edge]), gate partials
            #pragma unroll
            for (int mt = 0; mt < 4; ++mt) {
                const int m = mt * 16 + col;
                float g = 0.f;
                #pragma unroll
                for (int nt = 0; nt < 2; ++nt) {
                    const int fb = w * 32 + nt * 16 + quad * 4;
                    const float p0v = prelu_f(acc[mt][nt][0] + b1q[nt].x, a1);
                    const float p1v = prelu_f(acc[mt][nt][1] + b1q[nt].y, a1);
                    const float p2v = prelu_f(acc[mt][nt][2] + b1q[nt].z, a1);
                    const float p3v = prelu_f(acc[mt][nt][3] + b1q[nt].w, a1);
                    h2t[(fb + 0) * H2STR + m] = hs(p0v);
                    h2t[(fb + 1) * H2STR + m] = hs(p1v);
                    h2t[(fb + 2) * H2STR + m] = hs(p2v);
                    h2t[(fb + 3) * H2STR + m] = hs(p3v);
                    g += p0v * wgq[nt].x + p1v * wgq[nt].y + p2v * wgq[nt].z + p3v * wgq[nt].w;
                }
                g += __shfl_xor(g, 16);
                g += __shfl_xor(g, 32);
                if (quad == 0) gate_part[w][m] = g;
            }

            __syncthreads();   // B: h2t + gate_part visible; all h1 reads done

            // 4. combine NEXT tile into h1 (safe: reads drained at B);
            //    then refill eN with tile tt+2 indices (latency hidden by phase 5)
            if (pf) {
                #pragma unroll
                for (int i = 0; i < 4; ++i) {
                    uint4 hv;
                    hv.x = prelu2_add(sv[i].x, gv[i].x, a02);
                    hv.y = prelu2_add(sv[i].y, gv[i].y, a02);
                    hv.z = prelu2_add(sv[i].z, gv[i].z, a02);
                    hv.w = prelu2_add(sv[i].w, gv[i].w, a02);
                    *(uint4*)(h1 + (r0 + 16 * i) * HSTR + o * 8) = hv;
                    if (o == 0) il_lds[par ^ 1][r0 + 16 * i] = eN[i].y;
                }
                const int t2 = min(tt + 2, tc - 1);
                #pragma unroll
                for (int i = 0; i < 4; ++i)
                    eN[i] = jip[min(elo + t2 * 64 + r0 + 16 * i, ehi - 1)];
            }

            // 5. softmax weights + reduction-MFMA into REGISTER accumulator
            {
                const int ebase = elo + tt * 64;
                const int limit = min(64, ehi - ebase);   // valid edges in this tile
                hfrag bf2[2];
                float zp = 0.f;
                #pragma unroll
                for (int ks = 0; ks < 2; ++ks) {
                    const int e0 = ks * 32 + quad * 8;
                    const float4 ga0 = *(const float4*)&gate_part[0][e0];
                    const float4 ga1 = *(const float4*)&gate_part[1][e0];
                    const float4 ga2 = *(const float4*)&gate_part[2][e0];
                    const float4 ga3 = *(const float4*)&gate_part[3][e0];
                    const float4 gb0 = *(const float4*)&gate_part[0][e0 + 4];
                    const float4 gb1 = *(const float4*)&gate_part[1][e0 + 4];
                    const float4 gb2 = *(const float4*)&gate_part[2][e0 + 4];
                    const float4 gb3 = *(const float4*)&gate_part[3][e0 + 4];
                    const int4 ia = *(const int4*)&il_lds[par][e0];
                    const int4 ib = *(const int4*)&il_lds[par][e0 + 4];
                    // e = exp(min(gate, 11)): fp16-safe (e^11 < 65504)
                    const float e0v = __expf(fminf(ga0.x + ga1.x + ga2.x + ga3.x + c2, 11.f));
                    const float e1v = __expf(fminf(ga0.y + ga1.y + ga2.y + ga3.y + c2, 11.f));
                    const float e2v = __expf(fminf(ga0.z + ga1.z + ga2.z + ga3.z + c2, 11.f));
                    const float e3v = __expf(fminf(ga0.w + ga1.w + ga2.w + ga3.w + c2, 11.f));
                    const float e4v = __expf(fminf(gb0.x + gb1.x + gb2.x + gb3.x + c2, 11.f));
                    const float e5v = __expf(fminf(gb0.y + gb1.y + gb2.y + gb3.y + c2, 11.f));
                    const float e6v = __expf(fminf(gb0.z + gb1.z + gb2.z + gb3.z + c2, 11.f));
                    const float e7v = __expf(fminf(gb0.w + gb1.w + gb2.w + gb3.w + c2, 11.f));
                    // select node column (block owns cols 0..15); mask padded tail
                    const float s0 = (ia.x - n0 == col && e0 + 0 < limit) ? e0v : 0.f;
                    const float s1 = (ia.y - n0 == col && e0 + 1 < limit) ? e1v : 0.f;
                    const float s2 = (ia.z - n0 == col && e0 + 2 < limit) ? e2v : 0.f;
                    const float s3 = (ia.w - n0 == col && e0 + 3 < limit) ? e3v : 0.f;
                    const float s4 = (ib.x - n0 == col && e0 + 4 < limit) ? e4v : 0.f;
                    const float s5 = (ib.y - n0 == col && e0 + 5 < limit) ? e5v : 0.f;
                    const float s6 = (ib.z - n0 == col && e0 + 6 < limit) ? e6v : 0.f;
                    const float s7 = (ib.w - n0 == col && e0 + 7 < limit) ? e7v : 0.f;
                    zp += s0 + s1 + s2 + s3 + s4 + s5 + s6 + s7;
                    uint4 uu;
                    uu.x = pkh(s0, s1); uu.y = pkh(s2, s3);
                    uu.z = pkh(s4, s5); uu.w = pkh(s6, s7);
                    bf2[ks] = *(hfrag*)&uu;
                }
                // Z: reduce over quads -> per-tile Z[col]; accumulate in register
                float z = zp;
                z += __shfl_xor(z, 16);
                z += __shfl_xor(z, 32);
                zreg += z;
                // reduction MFMA: acc2 += h2t . E  (C-in accumulation across tiles)
                #pragma unroll
                for (int nt = 0; nt < 2; ++nt)
                    #pragma unroll
                    for (int ks = 0; ks < 2; ++ks) {
                        const hfrag a2 = *(const hfrag*)(
                            h2t + (w * 32 + nt * 16 + col) * H2STR + ks * 32 + quad * 8);
                        acc2[nt] = __builtin_amdgcn_mfma_f32_16x16x32_f16(
                            a2, bf2[ks], acc2[nt], 0, 0, 0);
                    }
            }

            par ^= 1;
        }
    }

    // epilogue (register-only, no barrier needed):
    // thread (w,quad,col) holds S[node=col][feat=w*32+nt*16+quad*4 ..+3], Z[col]
    const int node = n0 + col;
    if (node < N) {
        const float invz = 1.f / (zreg + 1e-16f);
        #pragma unroll
        for (int nt = 0; nt < 2; ++nt) {
            uint2 ov;
            ov.x = pkh(acc2[nt][0] * invz, acc2[nt][1] * invz);
            ov.y = pkh(acc2[nt][2] * invz, acc2[nt][3] * invz);
            *(uint2*)(aggh2 + (size_t)node * DIM + w * 32 + nt * 16 + quad * 4) = ov;
        }
    }
}

// ---------------------------------------------------------------------------
// K4: out = LN(aggh2 @ W2 + b2 + skip) * gamma + beta, via fp16 MFMA.
// ---------------------------------------------------------------------------
__global__ __launch_bounds__(256) void node_out_k(
    const unsigned short* __restrict__ aggh2,
    const unsigned short* __restrict__ W2t, const float* __restrict__ b2,
    const float* __restrict__ skip,
    const float* __restrict__ gamma, const float* __restrict__ beta,
    float* __restrict__ out, int N)
{
    __shared__ unsigned short hh[64 * HSTR];
    __shared__ float ls1[4][4][16], ls2[4][4][16];

    const int t = threadIdx.x;
    const int n0blk = blockIdx.x * 64;
    const int w = t >> 6, lane = t & 63, col = lane & 15, quad = lane >> 4;

    hfrag bw2[2][4];
    float4 b2q[2];
    #pragma unroll
    for (int nt = 0; nt < 2; ++nt) {
        const int n = w * 32 + nt * 16 + col;
        #pragma unroll
        for (int ks = 0; ks < 4; ++ks)
            bw2[nt][ks] = *(const hfrag*)(W2t + n * DIM + ks * 32 + quad * 8);
        b2q[nt] = *(const float4*)(b2 + w * 32 + nt * 16 + quad * 4);
    }

    for (int k = t; k < 64 * 16; k += 256) {
        const int row = k >> 4, oo = k & 15;
        uint4 v = make_uint4(0, 0, 0, 0);
        if (n0blk + row < N) v = *(const uint4*)(aggh2 + (size_t)(n0blk + row) * DIM + oo * 8);
        *(uint4*)(hh + row * HSTR + oo * 8) = v;
    }
    __syncthreads();

    f32x4 acc[4][2];
    #pragma unroll
    for (int mt = 0; mt < 4; ++mt)
        #pragma unroll
        for (int nt = 0; nt < 2; ++nt)
            acc[mt][nt] = f32x4{0.f, 0.f, 0.f, 0.f};

    #pragma unroll
    for (int mt = 0; mt < 4; ++mt) {
        hfrag af[4];
        #pragma unroll
        for (int ks = 0; ks < 4; ++ks)
            af[ks] = *(const hfrag*)(hh + (mt * 16 + col) * HSTR + ks * 32 + quad * 8);
        #pragma unroll
        for (int nt = 0; nt < 2; ++nt)
            #pragma unroll
            for (int ks = 0; ks < 4; ++ks)
                acc[mt][nt] = __builtin_amdgcn_mfma_f32_16x16x32_f16(
                    bw2[nt][ks], af[ks], acc[mt][nt], 0, 0, 0);
    }

    float v[4][2][4];
    #pragma unroll
    for (int mt = 0; mt < 4; ++mt) {
        const int node = n0blk + mt * 16 + col;
        float s1 = 0.f, s2 = 0.f;
        #pragma unroll
        for (int nt = 0; nt < 2; ++nt) {
            const int f0 = w * 32 + nt * 16 + quad * 4;
            float4 sk = make_float4(0.f, 0.f, 0.f, 0.f);
            if (node < N) sk = *(const float4*)(skip + (size_t)node * DIM + f0);
            v[mt][nt][0] = acc[mt][nt][0] + b2q[nt].x + sk.x;
            v[mt][nt][1] = acc[mt][nt][1] + b2q[nt].y + sk.y;
            v[mt][nt][2] = acc[mt][nt][2] + b2q[nt].z + sk.z;
            v[mt][nt][3] = acc[mt][nt][3] + b2q[nt].w + sk.w;
            #pragma unroll
            for (int r = 0; r < 4; ++r) {
                s1 += v[mt][nt][r];
                s2 += v[mt][nt][r] * v[mt][nt][r];
            }
        }
        s1 += __shfl_xor(s1, 16); s1 += __shfl_xor(s1, 32);
        s2 += __shfl_xor(s2, 16); s2 += __shfl_xor(s2, 32);
        if (quad == 0) { ls1[w][mt][col] = s1; ls2[w][mt][col] = s2; }
    }
    __syncthreads();

    #pragma unroll
    for (int mt = 0; mt < 4; ++mt) {
        const int node = n0blk + mt * 16 + col;
        if (node >= N) continue;
        const float sum = ls1[0][mt][col] + ls1[1][mt][col] + ls1[2][mt][col] + ls1[3][mt][col];
        const float sq  = ls2[0][mt][col] + ls2[1][mt][col] + ls2[2][mt][col] + ls2[3][mt][col];
        const float mu = sum * (1.f / 128.f);
        const float var = sq * (1.f / 128.f) - mu * mu;
        const float rs = rsqrtf(var + 1e-5f);
        #pragma unroll
        for (int nt = 0; nt < 2; ++nt) {
            const int f0 = w * 32 + nt * 16 + quad * 4;
            const float4 gm = *(const float4*)(gamma + f0);
            const float4 bt = *(const float4*)(beta + f0);
            float4 ov;
            ov.x = (v[mt][nt][0] - mu) * rs * gm.x + bt.x;
            ov.y = (v[mt][nt][1] - mu) * rs * gm.y + bt.y;
            ov.z = (v[mt][nt][2] - mu) * rs * gm.z + bt.z;
            ov.w = (v[mt][nt][3] - mu) * rs * gm.w + bt.w;
            *(float4*)(out + (size_t)node * DIM + f0) = ov;
        }
    }
}

// ---------------------------------------------------------------------------
extern "C" void kernel_launch(void* const* d_in, const int* in_sizes, int n_in,
                              void* d_out, int out_size, void* d_ws, size_t ws_size,
                              hipStream_t stream)
{
    const float* x     = (const float*)d_in[0];
    const int*   eidx  = (const int*)d_in[1];
    const float* Wsrc  = (const float*)d_in[2];
    const float* bsrc  = (const float*)d_in[3];
    const float* Wtgt  = (const float*)d_in[4];
    const float* Wskip = (const float*)d_in[5];
    const float* a0    = (const float*)d_in[6];
    const float* W1    = (const float*)d_in[7];
    const float* b1    = (const float*)d_in[8];
    const float* a1    = (const float*)d_in[9];
    const float* W2    = (const float*)d_in[10];
    const float* b2    = (const float*)d_in[11];
    const float* Wg    = (const float*)d_in[12];
    const float* gamma = (const float*)d_in[13];
    const float* beta  = (const float*)d_in[14];

    const int N = in_sizes[0] / DIM;      // 20000
    const int E = in_sizes[1] / 2;        // 640000
    const int Npad = ((N + 63) / 64) * 64;
    float* out = (float*)d_out;

    char* ws = (char*)d_ws;
    size_t off = 0;
    auto alloc = [&](size_t bytes) -> void* {
        void* p = ws + off;
        off += (bytes + 255) & ~(size_t)255;
        return p;
    };
    int*            deg     = (int*)alloc((size_t)N * 4);
    unsigned short* msg_src = (unsigned short*)alloc((size_t)N * DIM * 2);
    unsigned short* msg_tgt = (unsigned short*)alloc((size_t)N * DIM * 2);
    float*          skip    = (float*)alloc((size_t)N * DIM * 4);
    int*            rowptr  = (int*)alloc((size_t)(N + 1) * 4);
    int*            rank    = (int*)alloc((size_t)E * 4);
    int2*           jip     = (int2*)alloc((size_t)E * 8);
    unsigned short* Wall    = (unsigned short*)alloc((size_t)5 * DIM * DIM * 2);
    float*          w2g     = (float*)alloc((size_t)(DIM + 1) * 4);
    unsigned short* aggh2   = (unsigned short*)alloc((size_t)Npad * DIM * 2);
    (void)ws_size; (void)n_in; (void)out_size;

    (void)hipMemsetAsync(deg, 0, (size_t)N * 4, stream);

    const int nhist = (E + 255) / 256;
    prep_hist_k<<<nhist + (5 * DIM * DIM) / 256 + 1, 256, 0, stream>>>(
        Wsrc, Wtgt, Wskip, W1, W2, b2, Wg, Wall, w2g, eidx, E, deg, rank);

    scan_k<<<1, 256, 0, stream>>>(deg, rowptr, N);

    const int nscatter = (E + 255) / 256;
    const int nnode = (N + 31) / 32;
    scatter_node_k<<<nscatter + nnode, 256, 0, stream>>>(
        eidx, E, rowptr, rank, jip, nscatter,
        x, Wall, bsrc, msg_src, msg_tgt, skip, N);

    const int nblk = (N + NPB - 1) / NPB;
    edge_fused_node<<<nblk, 256, 0, stream>>>(jip, rowptr, N, msg_src, msg_tgt, a0,
                                              Wall + 3 * DIM * DIM, b1, a1,
                                              w2g, aggh2);

    node_out_k<<<Npad / 64, 256, 0, stream>>>(aggh2, Wall + 4 * DIM * DIM, b2, skip,
                                              gamma, beta, out, N);
}

// Round 6
// 250.125 us; speedup vs baseline: 1.1074x; 1.0040x over previous
//
#include <hip/hip_runtime.h>
#include <hip/hip_bf16.h>
#include <stdint.h>

// Problem constants (reference: N=20000, E=640000, C=D=M=128)
#define DIM 128
#define HSTR 136    // padded LDS row stride in fp16 elems (272 B, 16B-aligned rows)
#define H2STR 72    // h2t row stride in fp16 elems (144 B, 16B-aligned rows)
#define NPB 16      // nodes per block == MFMA N dim (enables register-S accumulate)
#define NMAX 20224  // LDS-staged scan capacity

using hfrag = __attribute__((ext_vector_type(8))) _Float16;  // 8 fp16 (4 VGPRs)
using h2v   = __attribute__((ext_vector_type(2))) _Float16;
using f32x4 = __attribute__((ext_vector_type(4))) float;     // MFMA C/D

__device__ __forceinline__ float prelu_f(float v, float a) { return v >= 0.f ? v : a * v; }

// pack 2 floats -> fp16x2 (RTZ, 1 inst). Builtin returns __fp16x2; bitcast.
__device__ __forceinline__ unsigned pkh(float a, float b) {
    auto h = __builtin_amdgcn_cvt_pkrtz(a, b);
    return *(unsigned*)&h;
}
__device__ __forceinline__ unsigned short hs(float v) {
    _Float16 h = (_Float16)v;
    return *(unsigned short*)&h;
}
// packed fp16 prelu of (s+g): min(h,0)*a + max(h,0)
__device__ __forceinline__ unsigned prelu2_add(unsigned su, unsigned gu, h2v a2) {
    h2v s = *(h2v*)&su, g = *(h2v*)&gu;
    h2v h = s + g;
    h2v z = {(_Float16)0.f, (_Float16)0.f};
    h2v mx = __builtin_elementwise_max(h, z);
    h2v mn = __builtin_elementwise_min(h, z);
    h2v r = mn * a2 + mx;
    return *(unsigned*)&r;
}

// ---------------------------------------------------------------------------
// Merged prep + hist. Hist also captures per-edge rank (coalesced store),
// so the later scatter needs NO atomics. Wall[m][n][k] = fp16(W_m[k][n]).
// ---------------------------------------------------------------------------
__global__ __launch_bounds__(256) void prep_hist_k(
    const float* __restrict__ Wsrc, const float* __restrict__ Wtgt,
    const float* __restrict__ Wskip, const float* __restrict__ W1,
    const float* __restrict__ W2, const float* __restrict__ b2,
    const float* __restrict__ Wg,
    unsigned short* __restrict__ Wall, float* __restrict__ w2g,
    const int* __restrict__ eidx, int E, int* __restrict__ deg,
    int* __restrict__ rank)
{
    const int nhist = (E + 255) / 256;
    if ((int)blockIdx.x < nhist) {
        const int e = blockIdx.x * 256 + threadIdx.x;
        if (e < E) rank[e] = atomicAdd(deg + eidx[(size_t)E + e], 1);
        return;
    }
    const int b = blockIdx.x - nhist;
    if (b == (5 * DIM * DIM) / 256) {   // w2g block
        const int k = threadIdx.x;
        if (k < DIM) {
            float s = 0.f;
            for (int d = 0; d < DIM; ++d) s += W2[k * DIM + d] * Wg[d];
            w2g[k] = s;
        } else if (k == DIM) {
            float s = 0.f;
            for (int d = 0; d < DIM; ++d) s += b2[d] * Wg[d];
            w2g[DIM] = s;
        }
        return;
    }
    const int idx = b * 256 + threadIdx.x;
    const int m = idx >> 14;
    const int r = idx & 16383;
    const int n = r >> 7, k = r & 127;
    const float* W = (m == 0) ? Wsrc : (m == 1) ? Wtgt : (m == 2) ? Wskip : (m == 3) ? W1 : W2;
    const _Float16 hv = (_Float16)W[k * DIM + n];   // RNE scalar cvt
    Wall[idx] = *(const unsigned short*)&hv;
}

// ---------------------------------------------------------------------------
// Single-block scan, LDS-staged, 1024 threads (was 256: the per-thread serial
// chunk of 79 dominated; at 1024 threads it's 20). rowptr only.
// ---------------------------------------------------------------------------
__global__ __launch_bounds__(1024) void scan_k(const int* __restrict__ deg,
                                               int* __restrict__ rowptr, int N)
{
    __shared__ int part[1024];
    const int t = threadIdx.x;

    if (N <= NMAX) {
        __shared__ int s[NMAX];
        for (int k = t; k < N; k += 1024) s[k] = deg[k];
        __syncthreads();

        const int chunk = (N + 1023) / 1024;
        const int lo = min(t * chunk, N), hi = min(lo + chunk, N);
        int sum = 0;
        for (int k = lo; k < hi; ++k) sum += s[k];
        part[t] = sum;
        __syncthreads();
        for (int off = 1; off < 1024; off <<= 1) {
            int u = (t >= off) ? part[t - off] : 0;
            __syncthreads();
            part[t] += u;
            __syncthreads();
        }
        int run = part[t] - sum;
        for (int k = lo; k < hi; ++k) { const int d = s[k]; s[k] = run; run += d; }
        __syncthreads();
        for (int k = t; k < N; k += 1024) rowptr[k] = s[k];
        if (t == 0) rowptr[N] = part[1023];
    } else {
        const int chunk = (N + 1023) / 1024;
        const int lo = min(t * chunk, N), hi = min(lo + chunk, N);
        int s = 0;
        for (int k = lo; k < hi; ++k) s += deg[k];
        part[t] = s;
        __syncthreads();
        for (int off = 1; off < 1024; off <<= 1) {
            int u = (t >= off) ? part[t - off] : 0;
            __syncthreads();
            part[t] += u;
            __syncthreads();
        }
        int run = part[t] - s;
        for (int k = lo; k < hi; ++k) {
            rowptr[k] = run;
            run += deg[k];
        }
        if (t == 1023) rowptr[N] = part[1023];
    }
}

// ---------------------------------------------------------------------------
// Merged scatter + node_linear. Scatter is atomic-free:
// p = rowptr[i] + rank[e] (rowptr L2-resident), fire-and-forget jip write.
// ---------------------------------------------------------------------------
__global__ __launch_bounds__(256) void scatter_node_k(
    const int* __restrict__ eidx, int E,
    const int* __restrict__ rowptr, const int* __restrict__ rank,
    int2* __restrict__ jip, int nscatter,
    const float* __restrict__ x,
    const unsigned short* __restrict__ Wall,
    const float* __restrict__ bsrc,
    unsigned short* __restrict__ msg_src, unsigned short* __restrict__ msg_tgt,
    float* __restrict__ skip, int N)
{
    if ((int)blockIdx.x < nscatter) {
        const int e = blockIdx.x * 256 + threadIdx.x;
        if (e < E) {
            const int j = eidx[e];
            const int i = eidx[(size_t)E + e];
            const int p = rowptr[i] + rank[e];
            jip[p] = make_int2(j, i);
        }
        return;
    }

    __shared__ unsigned short xt[32 * HSTR];
    const int t = threadIdx.x;
    const int n0blk = (blockIdx.x - nscatter) * 32;
    const int w = t >> 6, lane = t & 63, col = lane & 15, quad = lane >> 4;

    for (int k = t; k < 32 * 16; k += 256) {
        const int row = k >> 4, o = k & 15;
        uint4 v = make_uint4(0, 0, 0, 0);
        if (n0blk + row < N) {
            const float4 a = *(const float4*)(x + (size_t)(n0blk + row) * DIM + o * 8);
            const float4 b = *(const float4*)(x + (size_t)(n0blk + row) * DIM + o * 8 + 4);
            v.x = pkh(a.x, a.y); v.y = pkh(a.z, a.w);
            v.z = pkh(b.x, b.y); v.w = pkh(b.z, b.w);
        }
        *(uint4*)(xt + row * HSTR + o * 8) = v;
    }
    __syncthreads();

    hfrag af[2][4];
    #pragma unroll
    for (int mt = 0; mt < 2; ++mt)
        #pragma unroll
        for (int ks = 0; ks < 4; ++ks)
            af[mt][ks] = *(const hfrag*)(xt + (mt * 16 + col) * HSTR + ks * 32 + quad * 8);

    for (int m = 0; m < 3; ++m) {
        const unsigned short* Wt = Wall + m * DIM * DIM;
        hfrag bw[2][4];
        #pragma unroll
        for (int nt = 0; nt < 2; ++nt)
            #pragma unroll
            for (int ks = 0; ks < 4; ++ks)
                bw[nt][ks] = *(const hfrag*)(Wt + (w * 32 + nt * 16 + col) * DIM + ks * 32 + quad * 8);

        f32x4 acc[2][2];
        #pragma unroll
        for (int mt = 0; mt < 2; ++mt)
            #pragma unroll
            for (int nt = 0; nt < 2; ++nt)
                acc[mt][nt] = f32x4{0.f, 0.f, 0.f, 0.f};

        #pragma unroll
        for (int mt = 0; mt < 2; ++mt)
            #pragma unroll
            for (int nt = 0; nt < 2; ++nt)
                #pragma unroll
                for (int ks = 0; ks < 4; ++ks)
                    acc[mt][nt] = __builtin_amdgcn_mfma_f32_16x16x32_f16(
                        bw[nt][ks], af[mt][ks], acc[mt][nt], 0, 0, 0);

        #pragma unroll
        for (int mt = 0; mt < 2; ++mt) {
            const int node = n0blk + mt * 16 + col;
            if (node >= N) continue;
            #pragma unroll
            for (int nt = 0; nt < 2; ++nt) {
                const int f0 = w * 32 + nt * 16 + quad * 4;
                if (m == 2) {
                    float4 o;
                    o.x = acc[mt][nt][0]; o.y = acc[mt][nt][1];
                    o.z = acc[mt][nt][2]; o.w = acc[mt][nt][3];
                    *(float4*)(skip + (size_t)node * DIM + f0) = o;
                } else {
                    float b0 = 0.f, b1v = 0.f, b2v = 0.f, b3v = 0.f;
                    if (m == 0) {
                        const float4 bb = *(const float4*)(bsrc + f0);
                        b0 = bb.x; b1v = bb.y; b2v = bb.z; b3v = bb.w;
                    }
                    uint2 o;
                    o.x = pkh(acc[mt][nt][0] + b0, acc[mt][nt][1] + b1v);
                    o.y = pkh(acc[mt][nt][2] + b2v, acc[mt][nt][3] + b3v);
                    unsigned short* dst = (m == 0) ? msg_src : msg_tgt;
                    *(uint2*)(dst + (size_t)node * DIM + f0) = o;
                }
            }
        }
    }
}

// ---------------------------------------------------------------------------
// K2 (fused, node-partitioned): block b owns nodes [b*NPB, b*NPB+NPB).
// vs round 5: the block's 16 msg_tgt rows are staged in LDS once (every
// tile's 64 edges target only these rows), halving the per-tile global
// gather traffic (8 -> 4 uint4 loads/thread) and freeing 16 VGPRs.
// S accumulates in MFMA C registers (NPB == MFMA N dim); Z in a register.
// launch_bounds(256,2): (256,3) reliably triggers scratch spills (r2, r4).
// ---------------------------------------------------------------------------
__global__ __launch_bounds__(256, 2) void edge_fused_node(
    const int2* __restrict__ jip, const int* __restrict__ rowptr, int N,
    const unsigned short* __restrict__ msg_src, const unsigned short* __restrict__ msg_tgt,
    const float* __restrict__ a0p,
    const unsigned short* __restrict__ W1t, const float* __restrict__ b1,
    const float* __restrict__ a1p,
    const float* __restrict__ w2g,
    unsigned short* __restrict__ aggh2)
{
    __shared__ unsigned short h1[64 * HSTR];        // [edge][feat] for GEMM1 B (single)
    __shared__ unsigned short h2t[DIM * H2STR];     // [feat][edge] for MFMA2 A (wave-private rows)
    __shared__ unsigned short tgt_lds[NPB * HSTR];  // block's 16 msg_tgt rows
    __shared__ float gate_part[4][64];
    __shared__ int il_lds[2][64];                   // per-edge target i (parity-buffered)

    const int t = threadIdx.x;
    const float a0 = *a0p, a1 = *a1p;
    const h2v a02 = {(_Float16)a0, (_Float16)a0};
    const int w = t >> 6, lane = t & 63, col = lane & 15, quad = lane >> 4;
    const int o = t & 15, r0 = t >> 4;

    const int n0 = blockIdx.x * NPB;
    const int elo = rowptr[n0];
    const int ehi = rowptr[min(n0 + NPB, N)];
    const int tc = (ehi - elo + 63) >> 6;           // local tile count

    hfrag bw1[2][4];
    float4 b1q[2], wgq[2];
    #pragma unroll
    for (int nt = 0; nt < 2; ++nt) {
        const int n = w * 32 + nt * 16 + col;
        #pragma unroll
        for (int ks = 0; ks < 4; ++ks)
            bw1[nt][ks] = *(const hfrag*)(W1t + n * DIM + ks * 32 + quad * 8);
        const int nq = w * 32 + nt * 16 + quad * 4;
        b1q[nt] = *(const float4*)(b1 + nq);
        wgq[nt] = *(const float4*)(w2g + nq);
    }
    const float c2 = w2g[DIM];

    // stage the block's 16 msg_tgt rows (read-only for the whole block)
    for (int k = t; k < NPB * 16; k += 256) {
        const int row = k >> 4, oo = k & 15;
        const int node = n0 + row;
        uint4 v = make_uint4(0, 0, 0, 0);
        if (node < N) v = *(const uint4*)(msg_tgt + (size_t)node * DIM + oo * 8);
        *(uint4*)(tgt_lds + row * HSTR + oo * 8) = v;
    }
    __syncthreads();

    // persistent per-thread accumulators: S[node=col][feat slice] and Z[col]
    f32x4 acc2[2] = {f32x4{0.f, 0.f, 0.f, 0.f}, f32x4{0.f, 0.f, 0.f, 0.f}};
    float zreg = 0.f;

    if (tc > 0) {
        // prologue: gather+combine tile 0 into h1; prefetch tile-1 idx
        {
            int2 e0r[4];
            #pragma unroll
            for (int i = 0; i < 4; ++i)
                e0r[i] = jip[min(elo + r0 + 16 * i, ehi - 1)];
            #pragma unroll
            for (int i = 0; i < 4; ++i) {
                const uint4 sv = *(const uint4*)(msg_src + (size_t)e0r[i].x * DIM + o * 8);
                const uint4 gv = *(const uint4*)(tgt_lds + (e0r[i].y - n0) * HSTR + o * 8);
                uint4 hv;
                hv.x = prelu2_add(sv.x, gv.x, a02);
                hv.y = prelu2_add(sv.y, gv.y, a02);
                hv.z = prelu2_add(sv.z, gv.z, a02);
                hv.w = prelu2_add(sv.w, gv.w, a02);
                *(uint4*)(h1 + (r0 + 16 * i) * HSTR + o * 8) = hv;
                if (o == 0) il_lds[0][r0 + 16 * i] = e0r[i].y;
            }
        }
        int2 eN[4];
        {
            const int t1 = min(1, tc - 1);
            #pragma unroll
            for (int i = 0; i < 4; ++i)
                eN[i] = jip[min(elo + t1 * 64 + r0 + 16 * i, ehi - 1)];
        }

        int par = 0;

        for (int tt = 0; tt < tc; ++tt) {
            __syncthreads();   // A: h1+il[par] visible; prev phase-5 h2t/gate reads done

            const bool pf = (tt + 1 < tc);

            // 1. issue NEXT tile's src gathers only (tgt comes from LDS)
            uint4 sv[4];
            if (pf) {
                #pragma unroll
                for (int i = 0; i < 4; ++i)
                    sv[i] = *(const uint4*)(msg_src + (size_t)eN[i].x * DIM + o * 8);
            }

            // 2. GEMM1 (transposed, fp16) from h1
            f32x4 acc[4][2];
            #pragma unroll
            for (int mt = 0; mt < 4; ++mt)
                #pragma unroll
                for (int nt = 0; nt < 2; ++nt)
                    acc[mt][nt] = f32x4{0.f, 0.f, 0.f, 0.f};

            __builtin_amdgcn_s_setprio(1);
            #pragma unroll
            for (int mt = 0; mt < 4; ++mt) {
                hfrag af[4];
                #pragma unroll
                for (int ks = 0; ks < 4; ++ks)
                    af[ks] = *(const hfrag*)(h1 + (mt * 16 + col) * HSTR + ks * 32 + quad * 8);
                #pragma unroll
                for (int nt = 0; nt < 2; ++nt)
                    #pragma unroll
                    for (int ks = 0; ks < 4; ++ks)
                        acc[mt][nt] = __builtin_amdgcn_mfma_f32_16x16x32_f16(
                            bw1[nt][ks], af[ks], acc[mt][nt], 0, 0, 0);
            }
            __builtin_amdgcn_s_setprio(0);

            // 3. epilogue: prelu -> h2t (fp16, [feat][edge], wave-private rows),
            //    gate partials (cross-wave)
            #pragma unroll
            for (int mt = 0; mt < 4; ++mt) {
                const int m = mt * 16 + col;
                float g = 0.f;
                #pragma unroll
                for (int nt = 0; nt < 2; ++nt) {
                    const int fb = w * 32 + nt * 16 + quad * 4;
                    const float p0v = prelu_f(acc[mt][nt][0] + b1q[nt].x, a1);
                    const float p1v = prelu_f(acc[mt][nt][1] + b1q[nt].y, a1);
                    const float p2v = prelu_f(acc[mt][nt][2] + b1q[nt].z, a1);
                    const float p3v = prelu_f(acc[mt][nt][3] + b1q[nt].w, a1);
                    h2t[(fb + 0) * H2STR + m] = hs(p0v);
                    h2t[(fb + 1) * H2STR + m] = hs(p1v);
                    h2t[(fb + 2) * H2STR + m] = hs(p2v);
                    h2t[(fb + 3) * H2STR + m] = hs(p3v);
                    g += p0v * wgq[nt].x + p1v * wgq[nt].y + p2v * wgq[nt].z + p3v * wgq[nt].w;
                }
                g += __shfl_xor(g, 16);
                g += __shfl_xor(g, 32);
                if (quad == 0) gate_part[w][m] = g;
            }

            __syncthreads();   // B: h2t + gate_part visible; all h1 reads done

            // 4. combine NEXT tile into h1 (safe: reads drained at B);
            //    tgt side from LDS. Then refill eN with tile tt+2 indices.
            if (pf) {
                #pragma unroll
                for (int i = 0; i < 4; ++i) {
                    const uint4 gv = *(const uint4*)(tgt_lds + (eN[i].y - n0) * HSTR + o * 8);
                    uint4 hv;
                    hv.x = prelu2_add(sv[i].x, gv.x, a02);
                    hv.y = prelu2_add(sv[i].y, gv.y, a02);
                    hv.z = prelu2_add(sv[i].z, gv.z, a02);
                    hv.w = prelu2_add(sv[i].w, gv.w, a02);
                    *(uint4*)(h1 + (r0 + 16 * i) * HSTR + o * 8) = hv;
                    if (o == 0) il_lds[par ^ 1][r0 + 16 * i] = eN[i].y;
                }
                const int t2 = min(tt + 2, tc - 1);
                #pragma unroll
                for (int i = 0; i < 4; ++i)
                    eN[i] = jip[min(elo + t2 * 64 + r0 + 16 * i, ehi - 1)];
            }

            // 5. softmax weights + reduction-MFMA into REGISTER accumulator
            {
                const int ebase = elo + tt * 64;
                const int limit = min(64, ehi - ebase);   // valid edges in this tile
                hfrag bf2[2];
                float zp = 0.f;
                #pragma unroll
                for (int ks = 0; ks < 2; ++ks) {
                    const int e0 = ks * 32 + quad * 8;
                    const float4 ga0 = *(const float4*)&gate_part[0][e0];
                    const float4 ga1 = *(const float4*)&gate_part[1][e0];
                    const float4 ga2 = *(const float4*)&gate_part[2][e0];
                    const float4 ga3 = *(const float4*)&gate_part[3][e0];
                    const float4 gb0 = *(const float4*)&gate_part[0][e0 + 4];
                    const float4 gb1 = *(const float4*)&gate_part[1][e0 + 4];
                    const float4 gb2 = *(const float4*)&gate_part[2][e0 + 4];
                    const float4 gb3 = *(const float4*)&gate_part[3][e0 + 4];
                    const int4 ia = *(const int4*)&il_lds[par][e0];
                    const int4 ib = *(const int4*)&il_lds[par][e0 + 4];
                    // e = exp(min(gate, 11)): fp16-safe (e^11 < 65504)
                    const float e0v = __expf(fminf(ga0.x + ga1.x + ga2.x + ga3.x + c2, 11.f));
                    const float e1v = __expf(fminf(ga0.y + ga1.y + ga2.y + ga3.y + c2, 11.f));
                    const float e2v = __expf(fminf(ga0.z + ga1.z + ga2.z + ga3.z + c2, 11.f));
                    const float e3v = __expf(fminf(ga0.w + ga1.w + ga2.w + ga3.w + c2, 11.f));
                    const float e4v = __expf(fminf(gb0.x + gb1.x + gb2.x + gb3.x + c2, 11.f));
                    const float e5v = __expf(fminf(gb0.y + gb1.y + gb2.y + gb3.y + c2, 11.f));
                    const float e6v = __expf(fminf(gb0.z + gb1.z + gb2.z + gb3.z + c2, 11.f));
                    const float e7v = __expf(fminf(gb0.w + gb1.w + gb2.w + gb3.w + c2, 11.f));
                    // select node column (block owns cols 0..15); mask padded tail
                    const float s0 = (ia.x - n0 == col && e0 + 0 < limit) ? e0v : 0.f;
                    const float s1 = (ia.y - n0 == col && e0 + 1 < limit) ? e1v : 0.f;
                    const float s2 = (ia.z - n0 == col && e0 + 2 < limit) ? e2v : 0.f;
                    const float s3 = (ia.w - n0 == col && e0 + 3 < limit) ? e3v : 0.f;
                    const float s4 = (ib.x - n0 == col && e0 + 4 < limit) ? e4v : 0.f;
                    const float s5 = (ib.y - n0 == col && e0 + 5 < limit) ? e5v : 0.f;
                    const float s6 = (ib.z - n0 == col && e0 + 6 < limit) ? e6v : 0.f;
                    const float s7 = (ib.w - n0 == col && e0 + 7 < limit) ? e7v : 0.f;
                    zp += s0 + s1 + s2 + s3 + s4 + s5 + s6 + s7;
                    uint4 uu;
                    uu.x = pkh(s0, s1); uu.y = pkh(s2, s3);
                    uu.z = pkh(s4, s5); uu.w = pkh(s6, s7);
                    bf2[ks] = *(hfrag*)&uu;
                }
                // Z: reduce over quads -> per-tile Z[col]; accumulate in register
                float z = zp;
                z += __shfl_xor(z, 16);
                z += __shfl_xor(z, 32);
                zreg += z;
                // reduction MFMA: acc2 += h2t . E  (C-in accumulation across tiles)
                #pragma unroll
                for (int nt = 0; nt < 2; ++nt)
                    #pragma unroll
                    for (int ks = 0; ks < 2; ++ks) {
                        const hfrag a2 = *(const hfrag*)(
                            h2t + (w * 32 + nt * 16 + col) * H2STR + ks * 32 + quad * 8);
                        acc2[nt] = __builtin_amdgcn_mfma_f32_16x16x32_f16(
                            a2, bf2[ks], acc2[nt], 0, 0, 0);
                    }
            }

            par ^= 1;
        }
    }

    // epilogue (register-only, no barrier needed):
    // thread (w,quad,col) holds S[node=col][feat=w*32+nt*16+quad*4 ..+3], Z[col]
    const int node = n0 + col;
    if (node < N) {
        const float invz = 1.f / (zreg + 1e-16f);
        #pragma unroll
        for (int nt = 0; nt < 2; ++nt) {
            uint2 ov;
            ov.x = pkh(acc2[nt][0] * invz, acc2[nt][1] * invz);
            ov.y = pkh(acc2[nt][2] * invz, acc2[nt][3] * invz);
            *(uint2*)(aggh2 + (size_t)node * DIM + w * 32 + nt * 16 + quad * 4) = ov;
        }
    }
}

// ---------------------------------------------------------------------------
// K4: out = LN(aggh2 @ W2 + b2 + skip) * gamma + beta, via fp16 MFMA.
// ---------------------------------------------------------------------------
__global__ __launch_bounds__(256) void node_out_k(
    const unsigned short* __restrict__ aggh2,
    const unsigned short* __restrict__ W2t, const float* __restrict__ b2,
    const float* __restrict__ skip,
    const float* __restrict__ gamma, const float* __restrict__ beta,
    float* __restrict__ out, int N)
{
    __shared__ unsigned short hh[64 * HSTR];
    __shared__ float ls1[4][4][16], ls2[4][4][16];

    const int t = threadIdx.x;
    const int n0blk = blockIdx.x * 64;
    const int w = t >> 6, lane = t & 63, col = lane & 15, quad = lane >> 4;

    hfrag bw2[2][4];
    float4 b2q[2];
    #pragma unroll
    for (int nt = 0; nt < 2; ++nt) {
        const int n = w * 32 + nt * 16 + col;
        #pragma unroll
        for (int ks = 0; ks < 4; ++ks)
            bw2[nt][ks] = *(const hfrag*)(W2t + n * DIM + ks * 32 + quad * 8);
        b2q[nt] = *(const float4*)(b2 + w * 32 + nt * 16 + quad * 4);
    }

    for (int k = t; k < 64 * 16; k += 256) {
        const int row = k >> 4, oo = k & 15;
        uint4 v = make_uint4(0, 0, 0, 0);
        if (n0blk + row < N) v = *(const uint4*)(aggh2 + (size_t)(n0blk + row) * DIM + oo * 8);
        *(uint4*)(hh + row * HSTR + oo * 8) = v;
    }
    __syncthreads();

    f32x4 acc[4][2];
    #pragma unroll
    for (int mt = 0; mt < 4; ++mt)
        #pragma unroll
        for (int nt = 0; nt < 2; ++nt)
            acc[mt][nt] = f32x4{0.f, 0.f, 0.f, 0.f};

    #pragma unroll
    for (int mt = 0; mt < 4; ++mt) {
        hfrag af[4];
        #pragma unroll
        for (int ks = 0; ks < 4; ++ks)
            af[ks] = *(const hfrag*)(hh + (mt * 16 + col) * HSTR + ks * 32 + quad * 8);
        #pragma unroll
        for (int nt = 0; nt < 2; ++nt)
            #pragma unroll
            for (int ks = 0; ks < 4; ++ks)
                acc[mt][nt] = __builtin_amdgcn_mfma_f32_16x16x32_f16(
                    bw2[nt][ks], af[ks], acc[mt][nt], 0, 0, 0);
    }

    float v[4][2][4];
    #pragma unroll
    for (int mt = 0; mt < 4; ++mt) {
        const int node = n0blk + mt * 16 + col;
        float s1 = 0.f, s2 = 0.f;
        #pragma unroll
        for (int nt = 0; nt < 2; ++nt) {
            const int f0 = w * 32 + nt * 16 + quad * 4;
            float4 sk = make_float4(0.f, 0.f, 0.f, 0.f);
            if (node < N) sk = *(const float4*)(skip + (size_t)node * DIM + f0);
            v[mt][nt][0] = acc[mt][nt][0] + b2q[nt].x + sk.x;
            v[mt][nt][1] = acc[mt][nt][1] + b2q[nt].y + sk.y;
            v[mt][nt][2] = acc[mt][nt][2] + b2q[nt].z + sk.z;
            v[mt][nt][3] = acc[mt][nt][3] + b2q[nt].w + sk.w;
            #pragma unroll
            for (int r = 0; r < 4; ++r) {
                s1 += v[mt][nt][r];
                s2 += v[mt][nt][r] * v[mt][nt][r];
            }
        }
        s1 += __shfl_xor(s1, 16); s1 += __shfl_xor(s1, 32);
        s2 += __shfl_xor(s2, 16); s2 += __shfl_xor(s2, 32);
        if (quad == 0) { ls1[w][mt][col] = s1; ls2[w][mt][col] = s2; }
    }
    __syncthreads();

    #pragma unroll
    for (int mt = 0; mt < 4; ++mt) {
        const int node = n0blk + mt * 16 + col;
        if (node >= N) continue;
        const float sum = ls1[0][mt][col] + ls1[1][mt][col] + ls1[2][mt][col] + ls1[3][mt][col];
        const float sq  = ls2[0][mt][col] + ls2[1][mt][col] + ls2[2][mt][col] + ls2[3][mt][col];
        const float mu = sum * (1.f / 128.f);
        const float var = sq * (1.f / 128.f) - mu * mu;
        const float rs = rsqrtf(var + 1e-5f);
        #pragma unroll
        for (int nt = 0; nt < 2; ++nt) {
            const int f0 = w * 32 + nt * 16 + quad * 4;
            const float4 gm = *(const float4*)(gamma + f0);
            const float4 bt = *(const float4*)(beta + f0);
            float4 ov;
            ov.x = (v[mt][nt][0] - mu) * rs * gm.x + bt.x;
            ov.y = (v[mt][nt][1] - mu) * rs * gm.y + bt.y;
            ov.z = (v[mt][nt][2] - mu) * rs * gm.z + bt.z;
            ov.w = (v[mt][nt][3] - mu) * rs * gm.w + bt.w;
            *(float4*)(out + (size_t)node * DIM + f0) = ov;
        }
    }
}

// ---------------------------------------------------------------------------
extern "C" void kernel_launch(void* const* d_in, const int* in_sizes, int n_in,
                              void* d_out, int out_size, void* d_ws, size_t ws_size,
                              hipStream_t stream)
{
    const float* x     = (const float*)d_in[0];
    const int*   eidx  = (const int*)d_in[1];
    const float* Wsrc  = (const float*)d_in[2];
    const float* bsrc  = (const float*)d_in[3];
    const float* Wtgt  = (const float*)d_in[4];
    const float* Wskip = (const float*)d_in[5];
    const float* a0    = (const float*)d_in[6];
    const float* W1    = (const float*)d_in[7];
    const float* b1    = (const float*)d_in[8];
    const float* a1    = (const float*)d_in[9];
    const float* W2    = (const float*)d_in[10];
    const float* b2    = (const float*)d_in[11];
    const float* Wg    = (const float*)d_in[12];
    const float* gamma = (const float*)d_in[13];
    const float* beta  = (const float*)d_in[14];

    const int N = in_sizes[0] / DIM;      // 20000
    const int E = in_sizes[1] / 2;        // 640000
    const int Npad = ((N + 63) / 64) * 64;
    float* out = (float*)d_out;

    char* ws = (char*)d_ws;
    size_t off = 0;
    auto alloc = [&](size_t bytes) -> void* {
        void* p = ws + off;
        off += (bytes + 255) & ~(size_t)255;
        return p;
    };
    int*            deg     = (int*)alloc((size_t)N * 4);
    unsigned short* msg_src = (unsigned short*)alloc((size_t)N * DIM * 2);
    unsigned short* msg_tgt = (unsigned short*)alloc((size_t)N * DIM * 2);
    float*          skip    = (float*)alloc((size_t)N * DIM * 4);
    int*            rowptr  = (int*)alloc((size_t)(N + 1) * 4);
    int*            rank    = (int*)alloc((size_t)E * 4);
    int2*           jip     = (int2*)alloc((size_t)E * 8);
    unsigned short* Wall    = (unsigned short*)alloc((size_t)5 * DIM * DIM * 2);
    float*          w2g     = (float*)alloc((size_t)(DIM + 1) * 4);
    unsigned short* aggh2   = (unsigned short*)alloc((size_t)Npad * DIM * 2);
    (void)ws_size; (void)n_in; (void)out_size;

    (void)hipMemsetAsync(deg, 0, (size_t)N * 4, stream);

    const int nhist = (E + 255) / 256;
    prep_hist_k<<<nhist + (5 * DIM * DIM) / 256 + 1, 256, 0, stream>>>(
        Wsrc, Wtgt, Wskip, W1, W2, b2, Wg, Wall, w2g, eidx, E, deg, rank);

    scan_k<<<1, 1024, 0, stream>>>(deg, rowptr, N);

    const int nscatter = (E + 255) / 256;
    const int nnode = (N + 31) / 32;
    scatter_node_k<<<nscatter + nnode, 256, 0, stream>>>(
        eidx, E, rowptr, rank, jip, nscatter,
        x, Wall, bsrc, msg_src, msg_tgt, skip, N);

    const int nblk = (N + NPB - 1) / NPB;
    edge_fused_node<<<nblk, 256, 0, stream>>>(jip, rowptr, N, msg_src, msg_tgt, a0,
                                              Wall + 3 * DIM * DIM, b1, a1,
                                              w2g, aggh2);

    node_out_k<<<Npad / 64, 256, 0, stream>>>(aggh2, Wall + 4 * DIM * DIM, b2, skip,
                                              gamma, beta, out, N);
}

// Round 7
// 245.869 us; speedup vs baseline: 1.1266x; 1.0173x over previous
//
#include <hip/hip_runtime.h>
#include <hip/hip_bf16.h>
#include <stdint.h>

// Problem constants (reference: N=20000, E=640000, C=D=M=128)
#define DIM 128
#define HSTR 136    // padded LDS row stride in fp16 elems (272 B, 16B-aligned rows)
#define H2STR 72    // h2t row stride in fp16 elems (144 B, 16B-aligned rows)
#define NPB 16      // nodes per block == MFMA N dim (enables register-S accumulate)
#define NMAX 20224  // LDS-staged scan capacity

using hfrag = __attribute__((ext_vector_type(8))) _Float16;  // 8 fp16 (4 VGPRs)
using h2v   = __attribute__((ext_vector_type(2))) _Float16;
using f32x4 = __attribute__((ext_vector_type(4))) float;     // MFMA C/D

__device__ __forceinline__ float prelu_f(float v, float a) { return v >= 0.f ? v : a * v; }

// pack 2 floats -> fp16x2 (RTZ, 1 inst). Builtin returns __fp16x2; bitcast.
__device__ __forceinline__ unsigned pkh(float a, float b) {
    auto h = __builtin_amdgcn_cvt_pkrtz(a, b);
    return *(unsigned*)&h;
}
__device__ __forceinline__ unsigned short hs(float v) {
    _Float16 h = (_Float16)v;
    return *(unsigned short*)&h;
}
// packed fp16 prelu of (s+g): min(h,0)*a + max(h,0)
__device__ __forceinline__ unsigned prelu2_add(unsigned su, unsigned gu, h2v a2) {
    h2v s = *(h2v*)&su, g = *(h2v*)&gu;
    h2v h = s + g;
    h2v z = {(_Float16)0.f, (_Float16)0.f};
    h2v mx = __builtin_elementwise_max(h, z);
    h2v mn = __builtin_elementwise_min(h, z);
    h2v r = mn * a2 + mx;
    return *(unsigned*)&r;
}

// ---------------------------------------------------------------------------
// Merged prep + hist. Hist also captures per-edge rank (coalesced store),
// so the later scatter needs NO atomics. Wall[m][n][k] = fp16(W_m[k][n]).
// ---------------------------------------------------------------------------
__global__ __launch_bounds__(256) void prep_hist_k(
    const float* __restrict__ Wsrc, const float* __restrict__ Wtgt,
    const float* __restrict__ Wskip, const float* __restrict__ W1,
    const float* __restrict__ W2, const float* __restrict__ b2,
    const float* __restrict__ Wg,
    unsigned short* __restrict__ Wall, float* __restrict__ w2g,
    const int* __restrict__ eidx, int E, int* __restrict__ deg,
    int* __restrict__ rank)
{
    const int nhist = (E + 255) / 256;
    if ((int)blockIdx.x < nhist) {
        const int e = blockIdx.x * 256 + threadIdx.x;
        if (e < E) rank[e] = atomicAdd(deg + eidx[(size_t)E + e], 1);
        return;
    }
    const int b = blockIdx.x - nhist;
    if (b == (5 * DIM * DIM) / 256) {   // w2g block
        const int k = threadIdx.x;
        if (k < DIM) {
            float s = 0.f;
            for (int d = 0; d < DIM; ++d) s += W2[k * DIM + d] * Wg[d];
            w2g[k] = s;
        } else if (k == DIM) {
            float s = 0.f;
            for (int d = 0; d < DIM; ++d) s += b2[d] * Wg[d];
            w2g[DIM] = s;
        }
        return;
    }
    const int idx = b * 256 + threadIdx.x;
    const int m = idx >> 14;
    const int r = idx & 16383;
    const int n = r >> 7, k = r & 127;
    const float* W = (m == 0) ? Wsrc : (m == 1) ? Wtgt : (m == 2) ? Wskip : (m == 3) ? W1 : W2;
    const _Float16 hv = (_Float16)W[k * DIM + n];   // RNE scalar cvt
    Wall[idx] = *(const unsigned short*)&hv;
}

// ---------------------------------------------------------------------------
// Single-block scan, LDS-staged, 1024 threads. rowptr only.
// ---------------------------------------------------------------------------
__global__ __launch_bounds__(1024) void scan_k(const int* __restrict__ deg,
                                               int* __restrict__ rowptr, int N)
{
    __shared__ int part[1024];
    const int t = threadIdx.x;

    if (N <= NMAX) {
        __shared__ int s[NMAX];
        for (int k = t; k < N; k += 1024) s[k] = deg[k];
        __syncthreads();

        const int chunk = (N + 1023) / 1024;
        const int lo = min(t * chunk, N), hi = min(lo + chunk, N);
        int sum = 0;
        for (int k = lo; k < hi; ++k) sum += s[k];
        part[t] = sum;
        __syncthreads();
        for (int off = 1; off < 1024; off <<= 1) {
            int u = (t >= off) ? part[t - off] : 0;
            __syncthreads();
            part[t] += u;
            __syncthreads();
        }
        int run = part[t] - sum;
        for (int k = lo; k < hi; ++k) { const int d = s[k]; s[k] = run; run += d; }
        __syncthreads();
        for (int k = t; k < N; k += 1024) rowptr[k] = s[k];
        if (t == 0) rowptr[N] = part[1023];
    } else {
        const int chunk = (N + 1023) / 1024;
        const int lo = min(t * chunk, N), hi = min(lo + chunk, N);
        int s = 0;
        for (int k = lo; k < hi; ++k) s += deg[k];
        part[t] = s;
        __syncthreads();
        for (int off = 1; off < 1024; off <<= 1) {
            int u = (t >= off) ? part[t - off] : 0;
            __syncthreads();
            part[t] += u;
            __syncthreads();
        }
        int run = part[t] - s;
        for (int k = lo; k < hi; ++k) {
            rowptr[k] = run;
            run += deg[k];
        }
        if (t == 1023) rowptr[N] = part[1023];
    }
}

// ---------------------------------------------------------------------------
// Merged scatter + node_linear. Scatter is atomic-free:
// p = rowptr[i] + rank[e] (rowptr L2-resident), fire-and-forget jip write.
// ---------------------------------------------------------------------------
__global__ __launch_bounds__(256) void scatter_node_k(
    const int* __restrict__ eidx, int E,
    const int* __restrict__ rowptr, const int* __restrict__ rank,
    int2* __restrict__ jip, int nscatter,
    const float* __restrict__ x,
    const unsigned short* __restrict__ Wall,
    const float* __restrict__ bsrc,
    unsigned short* __restrict__ msg_src, unsigned short* __restrict__ msg_tgt,
    float* __restrict__ skip, int N)
{
    if ((int)blockIdx.x < nscatter) {
        const int e = blockIdx.x * 256 + threadIdx.x;
        if (e < E) {
            const int j = eidx[e];
            const int i = eidx[(size_t)E + e];
            const int p = rowptr[i] + rank[e];
            jip[p] = make_int2(j, i);
        }
        return;
    }

    __shared__ unsigned short xt[32 * HSTR];
    const int t = threadIdx.x;
    const int n0blk = (blockIdx.x - nscatter) * 32;
    const int w = t >> 6, lane = t & 63, col = lane & 15, quad = lane >> 4;

    for (int k = t; k < 32 * 16; k += 256) {
        const int row = k >> 4, o = k & 15;
        uint4 v = make_uint4(0, 0, 0, 0);
        if (n0blk + row < N) {
            const float4 a = *(const float4*)(x + (size_t)(n0blk + row) * DIM + o * 8);
            const float4 b = *(const float4*)(x + (size_t)(n0blk + row) * DIM + o * 8 + 4);
            v.x = pkh(a.x, a.y); v.y = pkh(a.z, a.w);
            v.z = pkh(b.x, b.y); v.w = pkh(b.z, b.w);
        }
        *(uint4*)(xt + row * HSTR + o * 8) = v;
    }
    __syncthreads();

    hfrag af[2][4];
    #pragma unroll
    for (int mt = 0; mt < 2; ++mt)
        #pragma unroll
        for (int ks = 0; ks < 4; ++ks)
            af[mt][ks] = *(const hfrag*)(xt + (mt * 16 + col) * HSTR + ks * 32 + quad * 8);

    for (int m = 0; m < 3; ++m) {
        const unsigned short* Wt = Wall + m * DIM * DIM;
        hfrag bw[2][4];
        #pragma unroll
        for (int nt = 0; nt < 2; ++nt)
            #pragma unroll
            for (int ks = 0; ks < 4; ++ks)
                bw[nt][ks] = *(const hfrag*)(Wt + (w * 32 + nt * 16 + col) * DIM + ks * 32 + quad * 8);

        f32x4 acc[2][2];
        #pragma unroll
        for (int mt = 0; mt < 2; ++mt)
            #pragma unroll
            for (int nt = 0; nt < 2; ++nt)
                acc[mt][nt] = f32x4{0.f, 0.f, 0.f, 0.f};

        #pragma unroll
        for (int mt = 0; mt < 2; ++mt)
            #pragma unroll
            for (int nt = 0; nt < 2; ++nt)
                #pragma unroll
                for (int ks = 0; ks < 4; ++ks)
                    acc[mt][nt] = __builtin_amdgcn_mfma_f32_16x16x32_f16(
                        bw[nt][ks], af[mt][ks], acc[mt][nt], 0, 0, 0);

        #pragma unroll
        for (int mt = 0; mt < 2; ++mt) {
            const int node = n0blk + mt * 16 + col;
            if (node >= N) continue;
            #pragma unroll
            for (int nt = 0; nt < 2; ++nt) {
                const int f0 = w * 32 + nt * 16 + quad * 4;
                if (m == 2) {
                    float4 o;
                    o.x = acc[mt][nt][0]; o.y = acc[mt][nt][1];
                    o.z = acc[mt][nt][2]; o.w = acc[mt][nt][3];
                    *(float4*)(skip + (size_t)node * DIM + f0) = o;
                } else {
                    float b0 = 0.f, b1v = 0.f, b2v = 0.f, b3v = 0.f;
                    if (m == 0) {
                        const float4 bb = *(const float4*)(bsrc + f0);
                        b0 = bb.x; b1v = bb.y; b2v = bb.z; b3v = bb.w;
                    }
                    uint2 o;
                    o.x = pkh(acc[mt][nt][0] + b0, acc[mt][nt][1] + b1v);
                    o.y = pkh(acc[mt][nt][2] + b2v, acc[mt][nt][3] + b3v);
                    unsigned short* dst = (m == 0) ? msg_src : msg_tgt;
                    *(uint2*)(dst + (size_t)node * DIM + f0) = o;
                }
            }
        }
    }
}

// ---------------------------------------------------------------------------
// K2 (fused, node-partitioned): block b owns nodes [b*NPB, b*NPB+NPB).
// Tile loop identical to round 6 (verified). NEW: node_out is fused into the
// epilogue — the block ends holding agg[16][128] in registers, so it writes
// the fp16 agg tile into LDS (aliasing h1; all h1 reads completed before the
// final barrier B), runs agg @ W2 + b2 + skip + LayerNorm with 8 MFMAs, and
// writes `out` directly. Deletes the node_out_k dispatch and the aggh2
// HBM round-trip (5 MB write + 5 MB read).
// launch_bounds(256,2): (256,3) reliably triggers scratch spills (r2, r4).
// ---------------------------------------------------------------------------
__global__ __launch_bounds__(256, 2) void edge_fused_node(
    const int2* __restrict__ jip, const int* __restrict__ rowptr, int N,
    const unsigned short* __restrict__ msg_src, const unsigned short* __restrict__ msg_tgt,
    const float* __restrict__ a0p,
    const unsigned short* __restrict__ W1t, const float* __restrict__ b1,
    const float* __restrict__ a1p,
    const float* __restrict__ w2g,
    const unsigned short* __restrict__ W2t, const float* __restrict__ b2,
    const float* __restrict__ skip,
    const float* __restrict__ gamma, const float* __restrict__ beta,
    float* __restrict__ out)
{
    __shared__ unsigned short h1[64 * HSTR];        // [edge][feat] for GEMM1 B (single)
    __shared__ unsigned short h2t[DIM * H2STR];     // [feat][edge] for MFMA2 A (wave-private rows)
    __shared__ unsigned short tgt_lds[NPB * HSTR];  // block's 16 msg_tgt rows
    __shared__ float gate_part[4][64];              // gate partials; reused as LN reduce scratch
    __shared__ int il_lds[2][64];                   // per-edge target i (parity-buffered)

    const int t = threadIdx.x;
    const float a0 = *a0p, a1 = *a1p;
    const h2v a02 = {(_Float16)a0, (_Float16)a0};
    const int w = t >> 6, lane = t & 63, col = lane & 15, quad = lane >> 4;
    const int o = t & 15, r0 = t >> 4;

    const int n0 = blockIdx.x * NPB;
    const int elo = rowptr[n0];
    const int ehi = rowptr[min(n0 + NPB, N)];
    const int tc = (ehi - elo + 63) >> 6;           // local tile count

    hfrag bw1[2][4];
    float4 b1q[2], wgq[2];
    #pragma unroll
    for (int nt = 0; nt < 2; ++nt) {
        const int n = w * 32 + nt * 16 + col;
        #pragma unroll
        for (int ks = 0; ks < 4; ++ks)
            bw1[nt][ks] = *(const hfrag*)(W1t + n * DIM + ks * 32 + quad * 8);
        const int nq = w * 32 + nt * 16 + quad * 4;
        b1q[nt] = *(const float4*)(b1 + nq);
        wgq[nt] = *(const float4*)(w2g + nq);
    }
    const float c2 = w2g[DIM];

    // stage the block's 16 msg_tgt rows (read-only for the whole block)
    for (int k = t; k < NPB * 16; k += 256) {
        const int row = k >> 4, oo = k & 15;
        const int node = n0 + row;
        uint4 v = make_uint4(0, 0, 0, 0);
        if (node < N) v = *(const uint4*)(msg_tgt + (size_t)node * DIM + oo * 8);
        *(uint4*)(tgt_lds + row * HSTR + oo * 8) = v;
    }
    __syncthreads();

    // persistent per-thread accumulators: S[node=col][feat slice] and Z[col]
    f32x4 acc2[2] = {f32x4{0.f, 0.f, 0.f, 0.f}, f32x4{0.f, 0.f, 0.f, 0.f}};
    float zreg = 0.f;

    if (tc > 0) {
        // prologue: gather+combine tile 0 into h1; prefetch tile-1 idx
        {
            int2 e0r[4];
            #pragma unroll
            for (int i = 0; i < 4; ++i)
                e0r[i] = jip[min(elo + r0 + 16 * i, ehi - 1)];
            #pragma unroll
            for (int i = 0; i < 4; ++i) {
                const uint4 sv = *(const uint4*)(msg_src + (size_t)e0r[i].x * DIM + o * 8);
                const uint4 gv = *(const uint4*)(tgt_lds + (e0r[i].y - n0) * HSTR + o * 8);
                uint4 hv;
                hv.x = prelu2_add(sv.x, gv.x, a02);
                hv.y = prelu2_add(sv.y, gv.y, a02);
                hv.z = prelu2_add(sv.z, gv.z, a02);
                hv.w = prelu2_add(sv.w, gv.w, a02);
                *(uint4*)(h1 + (r0 + 16 * i) * HSTR + o * 8) = hv;
                if (o == 0) il_lds[0][r0 + 16 * i] = e0r[i].y;
            }
        }
        int2 eN[4];
        {
            const int t1 = min(1, tc - 1);
            #pragma unroll
            for (int i = 0; i < 4; ++i)
                eN[i] = jip[min(elo + t1 * 64 + r0 + 16 * i, ehi - 1)];
        }

        int par = 0;

        for (int tt = 0; tt < tc; ++tt) {
            __syncthreads();   // A: h1+il[par] visible; prev phase-5 h2t/gate reads done

            const bool pf = (tt + 1 < tc);

            // 1. issue NEXT tile's src gathers only (tgt comes from LDS)
            uint4 sv[4];
            if (pf) {
                #pragma unroll
                for (int i = 0; i < 4; ++i)
                    sv[i] = *(const uint4*)(msg_src + (size_t)eN[i].x * DIM + o * 8);
            }

            // 2. GEMM1 (transposed, fp16) from h1
            f32x4 acc[4][2];
            #pragma unroll
            for (int mt = 0; mt < 4; ++mt)
                #pragma unroll
                for (int nt = 0; nt < 2; ++nt)
                    acc[mt][nt] = f32x4{0.f, 0.f, 0.f, 0.f};

            __builtin_amdgcn_s_setprio(1);
            #pragma unroll
            for (int mt = 0; mt < 4; ++mt) {
                hfrag af[4];
                #pragma unroll
                for (int ks = 0; ks < 4; ++ks)
                    af[ks] = *(const hfrag*)(h1 + (mt * 16 + col) * HSTR + ks * 32 + quad * 8);
                #pragma unroll
                for (int nt = 0; nt < 2; ++nt)
                    #pragma unroll
                    for (int ks = 0; ks < 4; ++ks)
                        acc[mt][nt] = __builtin_amdgcn_mfma_f32_16x16x32_f16(
                            bw1[nt][ks], af[ks], acc[mt][nt], 0, 0, 0);
            }
            __builtin_amdgcn_s_setprio(0);

            // 3. epilogue: prelu -> h2t (fp16, [feat][edge], wave-private rows),
            //    gate partials (cross-wave)
            #pragma unroll
            for (int mt = 0; mt < 4; ++mt) {
                const int m = mt * 16 + col;
                float g = 0.f;
                #pragma unroll
                for (int nt = 0; nt < 2; ++nt) {
                    const int fb = w * 32 + nt * 16 + quad * 4;
                    const float p0v = prelu_f(acc[mt][nt][0] + b1q[nt].x, a1);
                    const float p1v = prelu_f(acc[mt][nt][1] + b1q[nt].y, a1);
                    const float p2v = prelu_f(acc[mt][nt][2] + b1q[nt].z, a1);
                    const float p3v = prelu_f(acc[mt][nt][3] + b1q[nt].w, a1);
                    h2t[(fb + 0) * H2STR + m] = hs(p0v);
                    h2t[(fb + 1) * H2STR + m] = hs(p1v);
                    h2t[(fb + 2) * H2STR + m] = hs(p2v);
                    h2t[(fb + 3) * H2STR + m] = hs(p3v);
                    g += p0v * wgq[nt].x + p1v * wgq[nt].y + p2v * wgq[nt].z + p3v * wgq[nt].w;
                }
                g += __shfl_xor(g, 16);
                g += __shfl_xor(g, 32);
                if (quad == 0) gate_part[w][m] = g;
            }

            __syncthreads();   // B: h2t + gate_part visible; all h1 reads done

            // 4. combine NEXT tile into h1 (safe: reads drained at B);
            //    tgt side from LDS. Then refill eN with tile tt+2 indices.
            if (pf) {
                #pragma unroll
                for (int i = 0; i < 4; ++i) {
                    const uint4 gv = *(const uint4*)(tgt_lds + (eN[i].y - n0) * HSTR + o * 8);
                    uint4 hv;
                    hv.x = prelu2_add(sv[i].x, gv.x, a02);
                    hv.y = prelu2_add(sv[i].y, gv.y, a02);
                    hv.z = prelu2_add(sv[i].z, gv.z, a02);
                    hv.w = prelu2_add(sv[i].w, gv.w, a02);
                    *(uint4*)(h1 + (r0 + 16 * i) * HSTR + o * 8) = hv;
                    if (o == 0) il_lds[par ^ 1][r0 + 16 * i] = eN[i].y;
                }
                const int t2 = min(tt + 2, tc - 1);
                #pragma unroll
                for (int i = 0; i < 4; ++i)
                    eN[i] = jip[min(elo + t2 * 64 + r0 + 16 * i, ehi - 1)];
            }

            // 5. softmax weights + reduction-MFMA into REGISTER accumulator
            {
                const int ebase = elo + tt * 64;
                const int limit = min(64, ehi - ebase);   // valid edges in this tile
                hfrag bf2[2];
                float zp = 0.f;
                #pragma unroll
                for (int ks = 0; ks < 2; ++ks) {
                    const int e0 = ks * 32 + quad * 8;
                    const float4 ga0 = *(const float4*)&gate_part[0][e0];
                    const float4 ga1 = *(const float4*)&gate_part[1][e0];
                    const float4 ga2 = *(const float4*)&gate_part[2][e0];
                    const float4 ga3 = *(const float4*)&gate_part[3][e0];
                    const float4 gb0 = *(const float4*)&gate_part[0][e0 + 4];
                    const float4 gb1 = *(const float4*)&gate_part[1][e0 + 4];
                    const float4 gb2 = *(const float4*)&gate_part[2][e0 + 4];
                    const float4 gb3 = *(const float4*)&gate_part[3][e0 + 4];
                    const int4 ia = *(const int4*)&il_lds[par][e0];
                    const int4 ib = *(const int4*)&il_lds[par][e0 + 4];
                    // e = exp(min(gate, 11)): fp16-safe (e^11 < 65504)
                    const float e0v = __expf(fminf(ga0.x + ga1.x + ga2.x + ga3.x + c2, 11.f));
                    const float e1v = __expf(fminf(ga0.y + ga1.y + ga2.y + ga3.y + c2, 11.f));
                    const float e2v = __expf(fminf(ga0.z + ga1.z + ga2.z + ga3.z + c2, 11.f));
                    const float e3v = __expf(fminf(ga0.w + ga1.w + ga2.w + ga3.w + c2, 11.f));
                    const float e4v = __expf(fminf(gb0.x + gb1.x + gb2.x + gb3.x + c2, 11.f));
                    const float e5v = __expf(fminf(gb0.y + gb1.y + gb2.y + gb3.y + c2, 11.f));
                    const float e6v = __expf(fminf(gb0.z + gb1.z + gb2.z + gb3.z + c2, 11.f));
                    const float e7v = __expf(fminf(gb0.w + gb1.w + gb2.w + gb3.w + c2, 11.f));
                    // select node column (block owns cols 0..15); mask padded tail
                    const float s0 = (ia.x - n0 == col && e0 + 0 < limit) ? e0v : 0.f;
                    const float s1 = (ia.y - n0 == col && e0 + 1 < limit) ? e1v : 0.f;
                    const float s2 = (ia.z - n0 == col && e0 + 2 < limit) ? e2v : 0.f;
                    const float s3 = (ia.w - n0 == col && e0 + 3 < limit) ? e3v : 0.f;
                    const float s4 = (ib.x - n0 == col && e0 + 4 < limit) ? e4v : 0.f;
                    const float s5 = (ib.y - n0 == col && e0 + 5 < limit) ? e5v : 0.f;
                    const float s6 = (ib.z - n0 == col && e0 + 6 < limit) ? e6v : 0.f;
                    const float s7 = (ib.w - n0 == col && e0 + 7 < limit) ? e7v : 0.f;
                    zp += s0 + s1 + s2 + s3 + s4 + s5 + s6 + s7;
                    uint4 uu;
                    uu.x = pkh(s0, s1); uu.y = pkh(s2, s3);
                    uu.z = pkh(s4, s5); uu.w = pkh(s6, s7);
                    bf2[ks] = *(hfrag*)&uu;
                }
                // Z: reduce over quads -> per-tile Z[col]; accumulate in register
                float z = zp;
                z += __shfl_xor(z, 16);
                z += __shfl_xor(z, 32);
                zreg += z;
                // reduction MFMA: acc2 += h2t . E  (C-in accumulation across tiles)
                #pragma unroll
                for (int nt = 0; nt < 2; ++nt)
                    #pragma unroll
                    for (int ks = 0; ks < 2; ++ks) {
                        const hfrag a2 = *(const hfrag*)(
                            h2t + (w * 32 + nt * 16 + col) * H2STR + ks * 32 + quad * 8);
                        acc2[nt] = __builtin_amdgcn_mfma_f32_16x16x32_f16(
                            a2, bf2[ks], acc2[nt], 0, 0, 0);
                    }
            }

            par ^= 1;
        }
    }

    // -----------------------------------------------------------------------
    // Fused node-out epilogue: out = LN(agg @ W2 + b2 + skip) * gamma + beta.
    // agg tile -> LDS (alias h1: all h1 reads completed before final barrier B;
    // safe to overwrite even while other waves finish phase 5, which touches
    // only h2t/gate_part/il_lds).
    // -----------------------------------------------------------------------
    unsigned short* agg_lds = h1;
    {
        const float invz = 1.f / (zreg + 1e-16f);
        #pragma unroll
        for (int nt = 0; nt < 2; ++nt) {
            uint2 ov;
            ov.x = pkh(acc2[nt][0] * invz, acc2[nt][1] * invz);
            ov.y = pkh(acc2[nt][2] * invz, acc2[nt][3] * invz);
            *(uint2*)(agg_lds + col * HSTR + w * 32 + nt * 16 + quad * 4) = ov;
        }
    }
    __syncthreads();   // agg visible; all phase-5 work done (gate_part reusable)

    // W2 fragments + b2 (loaded only here -> no in-loop register pressure)
    hfrag bw2[2][4];
    float4 b2q[2];
    #pragma unroll
    for (int nt = 0; nt < 2; ++nt) {
        const int n = w * 32 + nt * 16 + col;
        #pragma unroll
        for (int ks = 0; ks < 4; ++ks)
            bw2[nt][ks] = *(const hfrag*)(W2t + n * DIM + ks * 32 + quad * 8);
        b2q[nt] = *(const float4*)(b2 + w * 32 + nt * 16 + quad * 4);
    }

    hfrag afo[4];
    #pragma unroll
    for (int ks = 0; ks < 4; ++ks)
        afo[ks] = *(const hfrag*)(agg_lds + col * HSTR + ks * 32 + quad * 8);

    f32x4 accO[2] = {f32x4{0.f, 0.f, 0.f, 0.f}, f32x4{0.f, 0.f, 0.f, 0.f}};
    #pragma unroll
    for (int nt = 0; nt < 2; ++nt)
        #pragma unroll
        for (int ks = 0; ks < 4; ++ks)
            accO[nt] = __builtin_amdgcn_mfma_f32_16x16x32_f16(
                bw2[nt][ks], afo[ks], accO[nt], 0, 0, 0);

    const int node = n0 + col;   // D row = col (same mapping as old node_out_k)
    float v[2][4];
    float s1 = 0.f, s2 = 0.f;
    #pragma unroll
    for (int nt = 0; nt < 2; ++nt) {
        const int f0 = w * 32 + nt * 16 + quad * 4;
        float4 sk = make_float4(0.f, 0.f, 0.f, 0.f);
        if (node < N) sk = *(const float4*)(skip + (size_t)node * DIM + f0);
        v[nt][0] = accO[nt][0] + b2q[nt].x + sk.x;
        v[nt][1] = accO[nt][1] + b2q[nt].y + sk.y;
        v[nt][2] = accO[nt][2] + b2q[nt].z + sk.z;
        v[nt][3] = accO[nt][3] + b2q[nt].w + sk.w;
        #pragma unroll
        for (int r = 0; r < 4; ++r) {
            s1 += v[nt][r];
            s2 += v[nt][r] * v[nt][r];
        }
    }
    s1 += __shfl_xor(s1, 16); s1 += __shfl_xor(s1, 32);
    s2 += __shfl_xor(s2, 16); s2 += __shfl_xor(s2, 32);
    if (quad == 0) { gate_part[w][col] = s1; gate_part[w][16 + col] = s2; }
    __syncthreads();

    if (node < N) {
        const float sum = gate_part[0][col] + gate_part[1][col]
                        + gate_part[2][col] + gate_part[3][col];
        const float sq  = gate_part[0][16 + col] + gate_part[1][16 + col]
                        + gate_part[2][16 + col] + gate_part[3][16 + col];
        const float mu = sum * (1.f / 128.f);
        const float var = sq * (1.f / 128.f) - mu * mu;
        const float rs = rsqrtf(var + 1e-5f);
        #pragma unroll
        for (int nt = 0; nt < 2; ++nt) {
            const int f0 = w * 32 + nt * 16 + quad * 4;
            const float4 gm = *(const float4*)(gamma + f0);
            const float4 bt = *(const float4*)(beta + f0);
            float4 ov;
            ov.x = (v[nt][0] - mu) * rs * gm.x + bt.x;
            ov.y = (v[nt][1] - mu) * rs * gm.y + bt.y;
            ov.z = (v[nt][2] - mu) * rs * gm.z + bt.z;
            ov.w = (v[nt][3] - mu) * rs * gm.w + bt.w;
            *(float4*)(out + (size_t)node * DIM + f0) = ov;
        }
    }
}

// ---------------------------------------------------------------------------
extern "C" void kernel_launch(void* const* d_in, const int* in_sizes, int n_in,
                              void* d_out, int out_size, void* d_ws, size_t ws_size,
                              hipStream_t stream)
{
    const float* x     = (const float*)d_in[0];
    const int*   eidx  = (const int*)d_in[1];
    const float* Wsrc  = (const float*)d_in[2];
    const float* bsrc  = (const float*)d_in[3];
    const float* Wtgt  = (const float*)d_in[4];
    const float* Wskip = (const float*)d_in[5];
    const float* a0    = (const float*)d_in[6];
    const float* W1    = (const float*)d_in[7];
    const float* b1    = (const float*)d_in[8];
    const float* a1    = (const float*)d_in[9];
    const float* W2    = (const float*)d_in[10];
    const float* b2    = (const float*)d_in[11];
    const float* Wg    = (const float*)d_in[12];
    const float* gamma = (const float*)d_in[13];
    const float* beta  = (const float*)d_in[14];

    const int N = in_sizes[0] / DIM;      // 20000
    const int E = in_sizes[1] / 2;        // 640000
    float* out = (float*)d_out;

    char* ws = (char*)d_ws;
    size_t off = 0;
    auto alloc = [&](size_t bytes) -> void* {
        void* p = ws + off;
        off += (bytes + 255) & ~(size_t)255;
        return p;
    };
    int*            deg     = (int*)alloc((size_t)N * 4);
    unsigned short* msg_src = (unsigned short*)alloc((size_t)N * DIM * 2);
    unsigned short* msg_tgt = (unsigned short*)alloc((size_t)N * DIM * 2);
    float*          skip    = (float*)alloc((size_t)N * DIM * 4);
    int*            rowptr  = (int*)alloc((size_t)(N + 1) * 4);
    int*            rank    = (int*)alloc((size_t)E * 4);
    int2*           jip     = (int2*)alloc((size_t)E * 8);
    unsigned short* Wall    = (unsigned short*)alloc((size_t)5 * DIM * DIM * 2);
    float*          w2g     = (float*)alloc((size_t)(DIM + 1) * 4);
    (void)ws_size; (void)n_in; (void)out_size;

    (void)hipMemsetAsync(deg, 0, (size_t)N * 4, stream);

    const int nhist = (E + 255) / 256;
    prep_hist_k<<<nhist + (5 * DIM * DIM) / 256 + 1, 256, 0, stream>>>(
        Wsrc, Wtgt, Wskip, W1, W2, b2, Wg, Wall, w2g, eidx, E, deg, rank);

    scan_k<<<1, 1024, 0, stream>>>(deg, rowptr, N);

    const int nscatter = (E + 255) / 256;
    const int nnode = (N + 31) / 32;
    scatter_node_k<<<nscatter + nnode, 256, 0, stream>>>(
        eidx, E, rowptr, rank, jip, nscatter,
        x, Wall, bsrc, msg_src, msg_tgt, skip, N);

    const int nblk = (N + NPB - 1) / NPB;
    edge_fused_node<<<nblk, 256, 0, stream>>>(jip, rowptr, N, msg_src, msg_tgt, a0,
                                              Wall + 3 * DIM * DIM, b1, a1, w2g,
                                              Wall + 4 * DIM * DIM, b2, skip,
                                              gamma, beta, out);
}